// Round 4
// baseline (99.176 us; speedup 1.0000x reference)
//
#include <hip/hip_runtime.h>
#include <hip/hip_bf16.h>
#include <math.h>

typedef __bf16 bf16x8 __attribute__((ext_vector_type(8)));
typedef float  f32x4  __attribute__((ext_vector_type(4)));

// ---------------- problem constants ----------------
#define BATCH 2
#define SEQ   256
#define DMODL 768
#define DIEXP 1536
#define NHEAD 24
#define HDIM  64
#define NSTATE 64
#define RRANK 2
#define NANG  16
#define HALFSPLIT 32
#define DINP  3416
#define DINP_PAD 3456     // 27*128
#define AFLOOR 1e-4f
#define EPSV   1e-5f

#define COL_Z    0
#define COL_X    1536
#define COL_B    3072
#define COL_C    3200
#define COL_DT   3328     // DTA strip starts here: DTA[c-3328][row]
#define COL_A    3352
#define COL_TRAP 3376
#define COL_ANG  3400

__device__ __forceinline__ float softplusf(float x) {
    if (x > 20.f) return x;
    return log1pf(expf(x));
}
__device__ __forceinline__ float sigmoidf_(float x) {
    return 1.f / (1.f + expf(-x));
}
__device__ __forceinline__ ushort f2bf(float f) {
    uint u = __float_as_uint(f);
    uint r = (u + 0x7FFFu + ((u >> 16) & 1u)) >> 16;
    return (ushort)r;
}

// ---------------- GEMM1: proj = u @ in_w^T (fp32 in, fused bf16 staging) -------
// BM=64, BN=128, BK=64, 4 waves (2x2), wave = 32x64. Double-buffered LDS with
// XOR swizzle (byte ^= (row&7)<<4). Side-writes transposed scalar strip to DTA.
__global__ __launch_bounds__(256) void gemm1(const float* __restrict__ A,
        const float* __restrict__ W, float* __restrict__ C, float* __restrict__ DTA,
        int Nw, int K, int Nstore) {
    const int bm = blockIdx.y * 64, bn = blockIdx.x * 128;
    const int tid = threadIdx.x;
    const int wv = tid >> 6, lane = tid & 63;
    const int wr = (wv >> 1) * 32, wc = (wv & 1) * 64;
    __shared__ ushort As[2][64 * 64];
    __shared__ ushort Bs[2][128 * 64];
    const int srow = tid >> 4, sc4 = tid & 15;
    const int NT = K >> 6;
    float4 ra[4], rw[8];

    auto load_tile = [&](int t) {
        const int k0 = t * 64;
        #pragma unroll
        for (int p = 0; p < 4; ++p)
            ra[p] = *(const float4*)(A + (size_t)(bm + p * 16 + srow) * K + k0 + sc4 * 4);
        #pragma unroll
        for (int p = 0; p < 8; ++p) {
            int r = p * 16 + srow;
            rw[p] = (bn + r < Nw)
                  ? *(const float4*)(W + (size_t)(bn + r) * K + k0 + sc4 * 4)
                  : (float4){0.f, 0.f, 0.f, 0.f};
        }
    };
    auto write_tile = [&](int buf) {
        #pragma unroll
        for (int p = 0; p < 4; ++p) {
            int r = p * 16 + srow;
            int byt = (sc4 * 8) ^ ((r & 7) << 4);
            ushort4 h;
            h.x = f2bf(ra[p].x); h.y = f2bf(ra[p].y);
            h.z = f2bf(ra[p].z); h.w = f2bf(ra[p].w);
            *(ushort4*)(&As[buf][r * 64 + (byt >> 1)]) = h;
        }
        #pragma unroll
        for (int p = 0; p < 8; ++p) {
            int r = p * 16 + srow;
            int byt = (sc4 * 8) ^ ((r & 7) << 4);
            ushort4 h;
            h.x = f2bf(rw[p].x); h.y = f2bf(rw[p].y);
            h.z = f2bf(rw[p].z); h.w = f2bf(rw[p].w);
            *(ushort4*)(&Bs[buf][r * 64 + (byt >> 1)]) = h;
        }
    };

    f32x4 acc[2][4];
    #pragma unroll
    for (int m = 0; m < 2; ++m)
        #pragma unroll
        for (int n = 0; n < 4; ++n) acc[m][n] = (f32x4){0.f, 0.f, 0.f, 0.f};
    const int fr = lane & 15, fk = (lane >> 4) * 16;

    auto compute = [&](int buf) {
        #pragma unroll
        for (int kk = 0; kk < 2; ++kk) {
            bf16x8 af[2], bff[4];
            #pragma unroll
            for (int m = 0; m < 2; ++m) {
                int r = wr + m * 16 + fr;
                int byt = (kk * 64 + fk) ^ ((r & 7) << 4);
                af[m] = *(const bf16x8*)(&As[buf][r * 64 + (byt >> 1)]);
            }
            #pragma unroll
            for (int n = 0; n < 4; ++n) {
                int r = wc + n * 16 + fr;
                int byt = (kk * 64 + fk) ^ ((r & 7) << 4);
                bff[n] = *(const bf16x8*)(&Bs[buf][r * 64 + (byt >> 1)]);
            }
            #pragma unroll
            for (int m = 0; m < 2; ++m)
                #pragma unroll
                for (int n = 0; n < 4; ++n)
                    acc[m][n] = __builtin_amdgcn_mfma_f32_16x16x32_bf16(af[m], bff[n], acc[m][n], 0, 0, 0);
        }
    };

    load_tile(0);
    write_tile(0);
    __syncthreads();
    for (int t = 0; t < NT; ++t) {
        if (t + 1 < NT) load_tile(t + 1);
        compute(t & 1);
        if (t + 1 < NT) write_tile((t + 1) & 1);
        __syncthreads();
    }

    const int r0 = bm + wr + (lane >> 4) * 4;
    #pragma unroll
    for (int n = 0; n < 4; ++n) {
        int col = bn + wc + n * 16 + fr;
        if (col >= 3328) {   // transposed side-strip for scan's coalesced reads
            #pragma unroll
            for (int m = 0; m < 2; ++m)
                #pragma unroll
                for (int r = 0; r < 4; ++r)
                    DTA[(size_t)(col - 3328) * 512 + r0 + m * 16 + r] = acc[m][n][r];
        }
        if (col >= Nstore) continue;
        #pragma unroll
        for (int m = 0; m < 2; ++m)
            #pragma unroll
            for (int r = 0; r < 4; ++r)
                C[(size_t)(r0 + m * 16 + r) * Nstore + col] = acc[m][n][r];
    }
}

// ---------------- GEMM2: out = Yc(bf16) @ out_w^T -------------------------------
// BM=64, BN=64, BK=64; A already bf16, W fp32 converted in staging.
__global__ __launch_bounds__(256) void gemm2(const ushort* __restrict__ A,
        const float* __restrict__ W, float* __restrict__ C, int K, int Nstore) {
    const int bm = blockIdx.y * 64, bn = blockIdx.x * 64;
    const int tid = threadIdx.x;
    const int wv = tid >> 6, lane = tid & 63;
    const int wr = (wv >> 1) * 32, wc = (wv & 1) * 32;
    __shared__ ushort As[2][64 * 64];
    __shared__ ushort Bs[2][64 * 64];
    const int srow = tid >> 4, sc4 = tid & 15;
    const int arow = tid >> 3, acol = (tid & 7) * 8;   // A: 2 x uint4 per thread
    const int NT = K >> 6;
    uint4 ra[2];
    float4 rw[4];

    auto load_tile = [&](int t) {
        const int k0 = t * 64;
        #pragma unroll
        for (int p = 0; p < 2; ++p)
            ra[p] = *(const uint4*)(A + (size_t)(bm + p * 32 + arow) * K + k0 + acol);
        #pragma unroll
        for (int p = 0; p < 4; ++p)
            rw[p] = *(const float4*)(W + (size_t)(bn + p * 16 + srow) * K + k0 + sc4 * 4);
    };
    auto write_tile = [&](int buf) {
        #pragma unroll
        for (int p = 0; p < 2; ++p) {
            int r = p * 32 + arow;
            int byt = (acol * 2) ^ ((r & 7) << 4);
            *(uint4*)(&As[buf][r * 64 + (byt >> 1)]) = ra[p];
        }
        #pragma unroll
        for (int p = 0; p < 4; ++p) {
            int r = p * 16 + srow;
            int byt = (sc4 * 8) ^ ((r & 7) << 4);
            ushort4 h;
            h.x = f2bf(rw[p].x); h.y = f2bf(rw[p].y);
            h.z = f2bf(rw[p].z); h.w = f2bf(rw[p].w);
            *(ushort4*)(&Bs[buf][r * 64 + (byt >> 1)]) = h;
        }
    };

    f32x4 acc[2][2];
    #pragma unroll
    for (int m = 0; m < 2; ++m)
        #pragma unroll
        for (int n = 0; n < 2; ++n) acc[m][n] = (f32x4){0.f, 0.f, 0.f, 0.f};
    const int fr = lane & 15, fk = (lane >> 4) * 16;

    auto compute = [&](int buf) {
        #pragma unroll
        for (int kk = 0; kk < 2; ++kk) {
            bf16x8 af[2], bff[2];
            #pragma unroll
            for (int m = 0; m < 2; ++m) {
                int r = wr + m * 16 + fr;
                int byt = (kk * 64 + fk) ^ ((r & 7) << 4);
                af[m] = *(const bf16x8*)(&As[buf][r * 64 + (byt >> 1)]);
            }
            #pragma unroll
            for (int n = 0; n < 2; ++n) {
                int r = wc + n * 16 + fr;
                int byt = (kk * 64 + fk) ^ ((r & 7) << 4);
                bff[n] = *(const bf16x8*)(&Bs[buf][r * 64 + (byt >> 1)]);
            }
            #pragma unroll
            for (int m = 0; m < 2; ++m)
                #pragma unroll
                for (int n = 0; n < 2; ++n)
                    acc[m][n] = __builtin_amdgcn_mfma_f32_16x16x32_bf16(af[m], bff[n], acc[m][n], 0, 0, 0);
        }
    };

    load_tile(0);
    write_tile(0);
    __syncthreads();
    for (int t = 0; t < NT; ++t) {
        if (t + 1 < NT) load_tile(t + 1);
        compute(t & 1);
        if (t + 1 < NT) write_tile((t + 1) & 1);
        __syncthreads();
    }

    const int r0 = bm + wr + (lane >> 4) * 4;
    #pragma unroll
    for (int n = 0; n < 2; ++n) {
        int col = bn + wc + n * 16 + fr;
        #pragma unroll
        for (int m = 0; m < 2; ++m)
            #pragma unroll
            for (int r = 0; r < 4; ++r)
                C[(size_t)(r0 + m * 16 + r) * Nstore + col] = acc[m][n][r];
    }
}

// ---------------- scan: per (b,h) scalars + wave-parallel cumsums ---------------
// All global reads are coalesced via the DTA transposed strip.
__global__ __launch_bounds__(256) void scan_kernel(const float* __restrict__ DTA,
        const float* __restrict__ dt_bias, float* __restrict__ DTv,
        float* __restrict__ lamv, float* __restrict__ Pc, float* __restrict__ theta) {
    const int bh = blockIdx.x;
    const int b = bh / NHEAD, h = bh % NHEAD;
    const int tid = threadIdx.x;
    __shared__ float mm[SEQ][18];
    const int l = tid;
    const int gl = b * SEQ + l;
    float DT  = softplusf(DTA[(size_t)h * 512 + gl] + dt_bias[h]);
    float Asp = fmaxf(softplusf(DTA[(size_t)(24 + h) * 512 + gl]), AFLOOR);
    float la  = -Asp * DT;
    float lam = sigmoidf_(DTA[(size_t)(48 + h) * 512 + gl]);
    DTv[bh * SEQ + l] = DT;
    lamv[bh * SEQ + l] = lam;
    #pragma unroll
    for (int i = 0; i < NANG; ++i) mm[l][i] = DT * DTA[(size_t)(72 + i) * 512 + gl];
    mm[l][16] = la;
    __syncthreads();
    const int wv = tid >> 6, lane = tid & 63;
    for (int ch = wv; ch < 17; ch += 4) {
        float carry = 0.f;
        for (int seg = 0; seg < 4; ++seg) {
            float v = mm[seg * 64 + lane][ch];
            #pragma unroll
            for (int off = 1; off < 64; off <<= 1) {
                float t = __shfl_up(v, off);
                if (lane >= off) v += t;
            }
            v += carry;
            carry = __shfl(v, 63);
            int ll = seg * 64 + lane;
            if (ch < 16)
                theta[((size_t)(b * SEQ + ll) * NHEAD + h) * NANG + ch] = v;
            else
                Pc[bh * SEQ + ll] = v;
        }
    }
}

// ---------------- prep3x: RMS+bias+RoPE -> Bh,Ch; also x -> XT (transposed) -----
__global__ __launch_bounds__(256) void prep3x(const float* __restrict__ proj,
        const float* __restrict__ Bbias, const float* __restrict__ Cbias,
        const float* __restrict__ Bnw, const float* __restrict__ Cnw,
        const float* __restrict__ theta,
        ushort* __restrict__ Bh, ushort* __restrict__ Ch, ushort* __restrict__ XT) {
    int bl = blockIdx.x;
    int b = bl / SEQ, l = bl % SEQ;
    int tid = threadIdx.x;
    __shared__ float sB[RRANK][NSTATE], sC[RRANK][NSTATE], scale[4];
    __shared__ float thl[NHEAD * NANG];
    const float* row = proj + (size_t)bl * DINP;
    if (tid < 128) {
        int r = tid / 64, n = tid % 64;
        sB[r][n] = row[COL_B + r * NSTATE + n];
    } else {
        int t2 = tid - 128;
        int r = t2 / 64, n = t2 % 64;
        sC[r][n] = row[COL_C + r * NSTATE + n];
    }
    for (int k = tid; k < NHEAD * NANG; k += 256)
        thl[k] = theta[(size_t)bl * NHEAD * NANG + k];
    __syncthreads();
    int g = tid / 64, lane = tid % 64;
    float v = (g < 2) ? sB[g][lane] : sC[g - 2][lane];
    float ss = v * v;
    #pragma unroll
    for (int off = 32; off; off >>= 1) ss += __shfl_xor(ss, off);
    if (lane == 0) scale[g] = rsqrtf(ss / NSTATE + EPSV);
    __syncthreads();
    float scB[2] = {scale[0], scale[1]};
    float scC[2] = {scale[2], scale[3]};
    for (int idx = tid; idx < RRANK * NHEAD * NSTATE; idx += 256) {
        int n = idx % NSTATE;
        int h = (idx / NSTATE) % NHEAD;
        int r = idx / (NSTATE * NHEAD);
        float outB, outC;
        if (n < HALFSPLIT) {
            int i = n >> 1;
            int n0 = i * 2, n1 = n0 + 1;
            float th = thl[h * NANG + i];
            float c = cosf(th), s = sinf(th);
            float b0 = sB[r][n0] * scB[r] * Bnw[n0] * Bbias[(h * RRANK + r) * NSTATE + n0];
            float b1 = sB[r][n1] * scB[r] * Bnw[n1] * Bbias[(h * RRANK + r) * NSTATE + n1];
            float c0 = sC[r][n0] * scC[r] * Cnw[n0] * Cbias[(h * RRANK + r) * NSTATE + n0];
            float c1 = sC[r][n1] * scC[r] * Cnw[n1] * Cbias[(h * RRANK + r) * NSTATE + n1];
            outB = (n & 1) ? (b0 * s + b1 * c) : (b0 * c - b1 * s);
            outC = (n & 1) ? (c0 * s + c1 * c) : (c0 * c - c1 * s);
        } else {
            outB = sB[r][n] * scB[r] * Bnw[n] * Bbias[(h * RRANK + r) * NSTATE + n];
            outC = sC[r][n] * scC[r] * Cnw[n] * Cbias[(h * RRANK + r) * NSTATE + n];
        }
        size_t o = ((size_t)((b * RRANK + r) * NHEAD + h) * SEQ + l) * NSTATE + n;
        Bh[o] = f2bf(outB);
        Ch[o] = f2bf(outC);
    }
    // x transpose: XT[(b*24+h)*64+p][l] = bf16(x)
    for (int idx = tid; idx < DIEXP; idx += 256) {
        float xv = row[COL_X + idx];
        XT[((size_t)b * NHEAD * HDIM + idx) * SEQ + l] = f2bf(xv);
    }
}

// ---------------- att2: MFMA scan + fused combine/gate --------------------------
// block = (bh, tt); handles BOTH r. 4 waves, wave w owns t-rows [tt*64+w*16,+16).
__global__ __launch_bounds__(256) void att2(const ushort* __restrict__ Bh,
        const ushort* __restrict__ Ch, const ushort* __restrict__ XT,
        const float* __restrict__ Pc, const float* __restrict__ DTv,
        const float* __restrict__ lamv, const float* __restrict__ proj,
        const float* __restrict__ mimo_x, const float* __restrict__ mimo_o,
        const float* __restrict__ Dvec, ushort* __restrict__ Yc) {
    const int bh = blockIdx.x, tt = blockIdx.y;
    const int b = bh / NHEAD, h = bh % NHEAD;
    const int tid = threadIdx.x, wv = tid >> 6, lane = tid & 63;
    __shared__ float Pl[SEQ], u1s[SEQ], u2s[SEQ];
    __shared__ ushort Pld[4][16][72];
    for (int t = tid; t < SEQ; t += 256) {
        Pl[t]  = Pc[bh * SEQ + t];
        u1s[t] = DTv[bh * SEQ + t] * lamv[bh * SEQ + t];
        u2s[t] = (t + 1 < SEQ) ? DTv[bh * SEQ + t + 1] * (1.f - lamv[bh * SEQ + t + 1]) : 0.f;
    }
    __syncthreads();
    const int r16 = lane & 15, kg = (lane >> 4) * 8;
    const int trow = tt * 64 + wv * 16;
    const int tr0 = trow + (lane >> 4) * 4;
    const int brh0 = (b * RRANK + 0) * NHEAD + h;
    const int brh1 = (b * RRANK + 1) * NHEAD + h;
    bf16x8 ca[2][2];
    {
        const ushort* cp0 = Ch + ((size_t)brh0 * SEQ + trow + r16) * NSTATE + kg;
        const ushort* cp1 = Ch + ((size_t)brh1 * SEQ + trow + r16) * NSTATE + kg;
        ca[0][0] = *(const bf16x8*)cp0;  ca[0][1] = *(const bf16x8*)(cp0 + 32);
        ca[1][0] = *(const bf16x8*)cp1;  ca[1][1] = *(const bf16x8*)(cp1 + 32);
    }
    f32x4 yacc[2][4];
    #pragma unroll
    for (int r2 = 0; r2 < 2; ++r2)
        #pragma unroll
        for (int pf = 0; pf < 4; ++pf) yacc[r2][pf] = (f32x4){0.f, 0.f, 0.f, 0.f};
    float Pt[4];
    #pragma unroll
    for (int r = 0; r < 4; ++r) Pt[r] = Pl[tr0 + r];
    float mmv[2][4];
    #pragma unroll
    for (int r2 = 0; r2 < 2; ++r2)
        #pragma unroll
        for (int pf = 0; pf < 4; ++pf) {
            int p = pf * 16 + r16;
            mmv[r2][pf] = mimo_x[(h * RRANK + r2) * HDIM + p] * mimo_o[(h * RRANK + r2) * HDIM + p];
        }
    const float Dh = Dvec[h];

    for (int jt = 0; jt <= tt; ++jt) {
        bf16x8 xf[4][2];
        #pragma unroll
        for (int pf = 0; pf < 4; ++pf) {
            const ushort* xp = XT + ((size_t)bh * HDIM + pf * 16 + r16) * SEQ + jt * 64 + kg;
            xf[pf][0] = *(const bf16x8*)xp;
            xf[pf][1] = *(const bf16x8*)(xp + 32);
        }
        #pragma unroll
        for (int r2 = 0; r2 < 2; ++r2) {
            const size_t bbase = (size_t)(r2 ? brh1 : brh0) * SEQ;
            #pragma unroll
            for (int nf = 0; nf < 4; ++nf) {
                const ushort* bp = Bh + (bbase + jt * 64 + nf * 16 + r16) * NSTATE + kg;
                bf16x8 b0 = *(const bf16x8*)bp;
                bf16x8 b1 = *(const bf16x8*)(bp + 32);
                f32x4 g = (f32x4){0.f, 0.f, 0.f, 0.f};
                g = __builtin_amdgcn_mfma_f32_16x16x32_bf16(ca[r2][0], b0, g, 0, 0, 0);
                g = __builtin_amdgcn_mfma_f32_16x16x32_bf16(ca[r2][1], b1, g, 0, 0, 0);
                const int j = jt * 64 + nf * 16 + r16;
                const float Pj = Pl[j], v1 = u1s[j], v2 = u2s[j];
                #pragma unroll
                for (int r = 0; r < 4; ++r) {
                    const int t = tr0 + r;
                    float wgt = 0.f;
                    if (j <= t) wgt = expf(Pt[r] - Pj) * (v1 + ((j < t) ? v2 : 0.f));
                    Pld[wv][(lane >> 4) * 4 + r][nf * 16 + r16] = f2bf(g[r] * wgt);
                }
            }
            bf16x8 pa0 = *(const bf16x8*)&Pld[wv][r16][kg];
            bf16x8 pa1 = *(const bf16x8*)&Pld[wv][r16][32 + kg];
            #pragma unroll
            for (int pf = 0; pf < 4; ++pf) {
                yacc[r2][pf] = __builtin_amdgcn_mfma_f32_16x16x32_bf16(pa0, xf[pf][0], yacc[r2][pf], 0, 0, 0);
                yacc[r2][pf] = __builtin_amdgcn_mfma_f32_16x16x32_bf16(pa1, xf[pf][1], yacc[r2][pf], 0, 0, 0);
            }
        }
    }
    // fused combine: y = y0*mm0 + y1*mm1 + D*x, gated by silu(z), -> bf16 Yc
    #pragma unroll
    for (int pf = 0; pf < 4; ++pf) {
        const int p = pf * 16 + r16;
        #pragma unroll
        for (int r = 0; r < 4; ++r) {
            const int t = tr0 + r;
            const float* rowp = proj + (size_t)(b * SEQ + t) * DINP;
            float xv = rowp[COL_X + h * HDIM + p];
            float zv = rowp[COL_Z + h * HDIM + p];
            float y = yacc[0][pf][r] * mmv[0][pf] + yacc[1][pf][r] * mmv[1][pf] + Dh * xv;
            y *= zv * sigmoidf_(zv);
            Yc[(size_t)(b * SEQ + t) * DIEXP + h * HDIM + p] = f2bf(y);
        }
    }
}

// ---------------- launch ----------------
extern "C" void kernel_launch(void* const* d_in, const int* in_sizes, int n_in,
                              void* d_out, int out_size, void* d_ws, size_t ws_size,
                              hipStream_t stream) {
    const float* u        = (const float*)d_in[0];
    const float* in_w     = (const float*)d_in[1];
    const float* dt_bias  = (const float*)d_in[2];
    const float* B_bias   = (const float*)d_in[3];
    const float* C_bias   = (const float*)d_in[4];
    const float* B_norm_w = (const float*)d_in[5];
    const float* C_norm_w = (const float*)d_in[6];
    const float* mimo_x   = (const float*)d_in[7];
    const float* mimo_o   = (const float*)d_in[8];
    const float* Dvec     = (const float*)d_in[9];
    const float* out_w    = (const float*)d_in[10];
    float* out = (float*)d_out;

    float* ws = (float*)d_ws;
    float*  proj  = ws;                           // 1,748,992 f
    float*  DTA   = proj + 1748992;               // 65,536 f (128 x 512)
    ushort* Bh_bf = (ushort*)(DTA + 65536);       // 786,432 f
    ushort* Ch_bf = (ushort*)(DTA + 851968);      // 786,432 f
    ushort* XT_bf = (ushort*)(DTA + 1638400);     // 393,216 f
    float*  theta = DTA + 2031616;                // 196,608 f
    float*  Pc    = DTA + 2228224;                // 12,288 f
    float*  DTv   = DTA + 2240512;                // 12,288 f
    float*  lamv  = DTA + 2252800;                // 12,288 f
    ushort* Yc_bf = (ushort*)(DTA + 2265088);     // 393,216 f  -> total ~17.8 MB

    // 1) proj = u @ in_proj_w^T (+ transposed DTA strip)
    gemm1<<<dim3(DINP_PAD / 128, 8), 256, 0, stream>>>(u, in_w, proj, DTA,
                                                       DINP, DMODL, DINP);
    // 2) scalars + wave-parallel cumsums (P, theta)
    scan_kernel<<<BATCH * NHEAD, 256, 0, stream>>>(DTA, dt_bias, DTv, lamv, Pc, theta);
    // 3) RMS + bias + RoPE -> bf16 Bh/Ch; x -> XT
    prep3x<<<BATCH * SEQ, 256, 0, stream>>>(proj, B_bias, C_bias, B_norm_w, C_norm_w,
                                            theta, Bh_bf, Ch_bf, XT_bf);
    // 4) MFMA scan + fused combine -> bf16 Yc
    att2<<<dim3(BATCH * NHEAD, 4), 256, 0, stream>>>(Bh_bf, Ch_bf, XT_bf, Pc, DTv,
                                                     lamv, proj, mimo_x, mimo_o,
                                                     Dvec, Yc_bf);
    // 5) out = Yc @ out_proj_w^T
    gemm2<<<dim3(DMODL / 64, 8), 256, 0, stream>>>(Yc_bf, out_w, out, DIEXP, DMODL);
}

// Round 5
// 83.612 us; speedup vs baseline: 1.1861x; 1.1861x over previous
//
#include <hip/hip_runtime.h>
#include <hip/hip_bf16.h>
#include <math.h>

typedef __bf16 bf16x8 __attribute__((ext_vector_type(8)));
typedef float  f32x4  __attribute__((ext_vector_type(4)));

// ---------------- problem constants ----------------
#define BATCH 2
#define SEQ   256
#define DMODL 768
#define DIEXP 1536
#define NHEAD 24
#define HDIM  64
#define NSTATE 64
#define RRANK 2
#define NANG  16
#define HALFSPLIT 32
#define DINP  3416
#define DINP_PAD 3456     // 54*64
#define AFLOOR 1e-4f
#define EPSV   1e-5f

#define COL_Z    0
#define COL_X    1536
#define COL_B    3072
#define COL_C    3200
#define COL_DT   3328     // DTA strip starts here: DTA[c-3328][row]
#define COL_A    3352
#define COL_TRAP 3376
#define COL_ANG  3400

__device__ __forceinline__ float softplusf(float x) {
    if (x > 20.f) return x;
    return log1pf(expf(x));
}
__device__ __forceinline__ float sigmoidf_(float x) {
    return 1.f / (1.f + expf(-x));
}
__device__ __forceinline__ ushort f2bf(float f) {
    uint u = __float_as_uint(f);
    uint r = (u + 0x7FFFu + ((u >> 16) & 1u)) >> 16;
    return (ushort)r;
}

// ---------------- GEMM1: proj = u @ in_w^T (fp32 in, fused bf16 staging) -------
// BM=64, BN=64, BK=64 -> 54x8 = 432 blocks (~1.7/CU for TLP latency hiding).
// 4 waves (2x2), wave = 32x32. XOR-swizzled double-buffered LDS.
// Side-writes transposed scalar strip (cols 3328..3455) to DTA for scan.
__global__ __launch_bounds__(256) void gemm1(const float* __restrict__ A,
        const float* __restrict__ W, float* __restrict__ C, float* __restrict__ DTA) {
    const int bm = blockIdx.y * 64, bn = blockIdx.x * 64;
    const int tid = threadIdx.x;
    const int wv = tid >> 6, lane = tid & 63;
    const int wr = (wv >> 1) * 32, wc = (wv & 1) * 32;
    __shared__ ushort As[2][64 * 64];
    __shared__ ushort Bs[2][64 * 64];
    const int srow = tid >> 4, sc4 = tid & 15;
    const int NT = DMODL >> 6;   // 12
    float4 ra[4], rw[4];

    auto load_tile = [&](int t) {
        const int k0 = t * 64;
        #pragma unroll
        for (int p = 0; p < 4; ++p)
            ra[p] = *(const float4*)(A + (size_t)(bm + p * 16 + srow) * DMODL + k0 + sc4 * 4);
        #pragma unroll
        for (int p = 0; p < 4; ++p) {
            int r = p * 16 + srow;
            rw[p] = (bn + r < DINP)
                  ? *(const float4*)(W + (size_t)(bn + r) * DMODL + k0 + sc4 * 4)
                  : (float4){0.f, 0.f, 0.f, 0.f};
        }
    };
    auto write_tile = [&](int buf) {
        #pragma unroll
        for (int p = 0; p < 4; ++p) {
            int r = p * 16 + srow;
            int byt = (sc4 * 8) ^ ((r & 7) << 4);
            ushort4 h;
            h.x = f2bf(ra[p].x); h.y = f2bf(ra[p].y);
            h.z = f2bf(ra[p].z); h.w = f2bf(ra[p].w);
            *(ushort4*)(&As[buf][r * 64 + (byt >> 1)]) = h;
        }
        #pragma unroll
        for (int p = 0; p < 4; ++p) {
            int r = p * 16 + srow;
            int byt = (sc4 * 8) ^ ((r & 7) << 4);
            ushort4 h;
            h.x = f2bf(rw[p].x); h.y = f2bf(rw[p].y);
            h.z = f2bf(rw[p].z); h.w = f2bf(rw[p].w);
            *(ushort4*)(&Bs[buf][r * 64 + (byt >> 1)]) = h;
        }
    };

    f32x4 acc[2][2];
    #pragma unroll
    for (int m = 0; m < 2; ++m)
        #pragma unroll
        for (int n = 0; n < 2; ++n) acc[m][n] = (f32x4){0.f, 0.f, 0.f, 0.f};
    const int fr = lane & 15, fk = (lane >> 4) * 16;

    auto compute = [&](int buf) {
        #pragma unroll
        for (int kk = 0; kk < 2; ++kk) {
            bf16x8 af[2], bff[2];
            #pragma unroll
            for (int m = 0; m < 2; ++m) {
                int r = wr + m * 16 + fr;
                int byt = (kk * 64 + fk) ^ ((r & 7) << 4);
                af[m] = *(const bf16x8*)(&As[buf][r * 64 + (byt >> 1)]);
            }
            #pragma unroll
            for (int n = 0; n < 2; ++n) {
                int r = wc + n * 16 + fr;
                int byt = (kk * 64 + fk) ^ ((r & 7) << 4);
                bff[n] = *(const bf16x8*)(&Bs[buf][r * 64 + (byt >> 1)]);
            }
            #pragma unroll
            for (int m = 0; m < 2; ++m)
                #pragma unroll
                for (int n = 0; n < 2; ++n)
                    acc[m][n] = __builtin_amdgcn_mfma_f32_16x16x32_bf16(af[m], bff[n], acc[m][n], 0, 0, 0);
        }
    };

    load_tile(0);
    write_tile(0);
    __syncthreads();
    for (int t = 0; t < NT; ++t) {
        if (t + 1 < NT) load_tile(t + 1);
        compute(t & 1);
        if (t + 1 < NT) write_tile((t + 1) & 1);
        __syncthreads();
    }

    const int r0 = bm + wr + (lane >> 4) * 4;
    #pragma unroll
    for (int n = 0; n < 2; ++n) {
        int col = bn + wc + n * 16 + fr;
        if (col >= 3328) {   // transposed side-strip for scan's coalesced reads
            #pragma unroll
            for (int m = 0; m < 2; ++m)
                #pragma unroll
                for (int r = 0; r < 4; ++r)
                    DTA[(size_t)(col - 3328) * 512 + r0 + m * 16 + r] = acc[m][n][r];
        }
        if (col >= DINP) continue;
        #pragma unroll
        for (int m = 0; m < 2; ++m)
            #pragma unroll
            for (int r = 0; r < 4; ++r)
                C[(size_t)(r0 + m * 16 + r) * DINP + col] = acc[m][n][r];
    }
}

// ---------------- GEMM2 split-K: Part[s] = Yc(bf16) @ out_w^T over K-slice s ----
// BM=64, BN=64, 4 K-slices of 384 -> 12x8x4 = 384 blocks, 6 iters each.
__global__ __launch_bounds__(256) void gemm2(const ushort* __restrict__ A,
        const float* __restrict__ W, float* __restrict__ Part) {
    const int bm = blockIdx.y * 64, bn = blockIdx.x * 64, ks = blockIdx.z;
    const int kbase = ks * 384;
    const int tid = threadIdx.x;
    const int wv = tid >> 6, lane = tid & 63;
    const int wr = (wv >> 1) * 32, wc = (wv & 1) * 32;
    __shared__ ushort As[2][64 * 64];
    __shared__ ushort Bs[2][64 * 64];
    const int srow = tid >> 4, sc4 = tid & 15;
    const int arow = tid >> 3, acol = (tid & 7) * 8;
    const int NT = 6;
    uint4 ra[2];
    float4 rw[4];

    auto load_tile = [&](int t) {
        const int k0 = kbase + t * 64;
        #pragma unroll
        for (int p = 0; p < 2; ++p)
            ra[p] = *(const uint4*)(A + (size_t)(bm + p * 32 + arow) * DIEXP + k0 + acol);
        #pragma unroll
        for (int p = 0; p < 4; ++p)
            rw[p] = *(const float4*)(W + (size_t)(bn + p * 16 + srow) * DIEXP + k0 + sc4 * 4);
    };
    auto write_tile = [&](int buf) {
        #pragma unroll
        for (int p = 0; p < 2; ++p) {
            int r = p * 32 + arow;
            int byt = (acol * 2) ^ ((r & 7) << 4);
            *(uint4*)(&As[buf][r * 64 + (byt >> 1)]) = ra[p];
        }
        #pragma unroll
        for (int p = 0; p < 4; ++p) {
            int r = p * 16 + srow;
            int byt = (sc4 * 8) ^ ((r & 7) << 4);
            ushort4 h;
            h.x = f2bf(rw[p].x); h.y = f2bf(rw[p].y);
            h.z = f2bf(rw[p].z); h.w = f2bf(rw[p].w);
            *(ushort4*)(&Bs[buf][r * 64 + (byt >> 1)]) = h;
        }
    };

    f32x4 acc[2][2];
    #pragma unroll
    for (int m = 0; m < 2; ++m)
        #pragma unroll
        for (int n = 0; n < 2; ++n) acc[m][n] = (f32x4){0.f, 0.f, 0.f, 0.f};
    const int fr = lane & 15, fk = (lane >> 4) * 16;

    auto compute = [&](int buf) {
        #pragma unroll
        for (int kk = 0; kk < 2; ++kk) {
            bf16x8 af[2], bff[2];
            #pragma unroll
            for (int m = 0; m < 2; ++m) {
                int r = wr + m * 16 + fr;
                int byt = (kk * 64 + fk) ^ ((r & 7) << 4);
                af[m] = *(const bf16x8*)(&As[buf][r * 64 + (byt >> 1)]);
            }
            #pragma unroll
            for (int n = 0; n < 2; ++n) {
                int r = wc + n * 16 + fr;
                int byt = (kk * 64 + fk) ^ ((r & 7) << 4);
                bff[n] = *(const bf16x8*)(&Bs[buf][r * 64 + (byt >> 1)]);
            }
            #pragma unroll
            for (int m = 0; m < 2; ++m)
                #pragma unroll
                for (int n = 0; n < 2; ++n)
                    acc[m][n] = __builtin_amdgcn_mfma_f32_16x16x32_bf16(af[m], bff[n], acc[m][n], 0, 0, 0);
        }
    };

    load_tile(0);
    write_tile(0);
    __syncthreads();
    for (int t = 0; t < NT; ++t) {
        if (t + 1 < NT) load_tile(t + 1);
        compute(t & 1);
        if (t + 1 < NT) write_tile((t + 1) & 1);
        __syncthreads();
    }

    const int r0 = bm + wr + (lane >> 4) * 4;
    float* P = Part + (size_t)ks * 512 * DMODL;
    #pragma unroll
    for (int n = 0; n < 2; ++n) {
        int col = bn + wc + n * 16 + fr;
        #pragma unroll
        for (int m = 0; m < 2; ++m)
            #pragma unroll
            for (int r = 0; r < 4; ++r)
                P[(size_t)(r0 + m * 16 + r) * DMODL + col] = acc[m][n][r];
    }
}

// ---------------- reduce4: out = sum_s Part[s] ----------------------------------
__global__ void reduce4(const float* __restrict__ Part, float* __restrict__ out) {
    const int i = blockIdx.x * 256 + threadIdx.x;   // float4 index, 98304 total
    const float4* p4 = (const float4*)Part;
    float4 a = p4[i];
    float4 b = p4[i + 98304];
    float4 c = p4[i + 196608];
    float4 d = p4[i + 294912];
    float4 r;
    r.x = a.x + b.x + c.x + d.x;
    r.y = a.y + b.y + c.y + d.y;
    r.z = a.z + b.z + c.z + d.z;
    r.w = a.w + b.w + c.w + d.w;
    ((float4*)out)[i] = r;
}

// ---------------- scan: scalars + cumsums + tiled x-transpose (per b,h) --------
__global__ __launch_bounds__(256) void scan_kernel(const float* __restrict__ DTA,
        const float* __restrict__ proj, const float* __restrict__ dt_bias,
        float* __restrict__ DTv, float* __restrict__ lamv, float* __restrict__ Pc,
        float* __restrict__ theta, ushort* __restrict__ XT) {
    const int bh = blockIdx.x;
    const int b = bh / NHEAD, h = bh % NHEAD;
    const int tid = threadIdx.x;
    __shared__ float mm[SEQ][18];
    __shared__ ushort tile[64][66];
    const int l = tid;
    const int gl = b * SEQ + l;
    float DT  = softplusf(DTA[(size_t)h * 512 + gl] + dt_bias[h]);
    float Asp = fmaxf(softplusf(DTA[(size_t)(24 + h) * 512 + gl]), AFLOOR);
    float la  = -Asp * DT;
    float lam = sigmoidf_(DTA[(size_t)(48 + h) * 512 + gl]);
    DTv[bh * SEQ + l] = DT;
    lamv[bh * SEQ + l] = lam;
    #pragma unroll
    for (int i = 0; i < NANG; ++i) mm[l][i] = DT * DTA[(size_t)(72 + i) * 512 + gl];
    mm[l][16] = la;
    __syncthreads();
    const int wv = tid >> 6, lane = tid & 63;
    for (int ch = wv; ch < 17; ch += 4) {
        float carry = 0.f;
        for (int seg = 0; seg < 4; ++seg) {
            float v = mm[seg * 64 + lane][ch];
            #pragma unroll
            for (int off = 1; off < 64; off <<= 1) {
                float t = __shfl_up(v, off);
                if (lane >= off) v += t;
            }
            v += carry;
            carry = __shfl(v, 63);
            int ll = seg * 64 + lane;
            if (ch < 16)
                theta[((size_t)(b * SEQ + ll) * NHEAD + h) * NANG + ch] = v;
            else
                Pc[bh * SEQ + ll] = v;
        }
    }
    // tiled x-transpose: XT[(bh*64+p)*SEQ + l] = bf16(x[b,l,h,p]) (coalesced both sides)
    for (int jt = 0; jt < 4; ++jt) {
        __syncthreads();
        for (int i = tid; i < 4096; i += 256) {
            int j = i >> 6, p = i & 63;
            tile[j][p] = f2bf(proj[(size_t)(b * SEQ + jt * 64 + j) * DINP + COL_X + h * HDIM + p]);
        }
        __syncthreads();
        for (int i = tid; i < 4096; i += 256) {
            int p = i >> 6, j = i & 63;
            XT[((size_t)bh * HDIM + p) * SEQ + jt * 64 + j] = tile[j][p];
        }
    }
}

// ---------------- prep3: RMS-norm + bias + RoPE -> bf16 Bh, Ch ------------------
__global__ __launch_bounds__(256) void prep3(const float* __restrict__ proj,
        const float* __restrict__ Bbias, const float* __restrict__ Cbias,
        const float* __restrict__ Bnw, const float* __restrict__ Cnw,
        const float* __restrict__ theta,
        ushort* __restrict__ Bh, ushort* __restrict__ Ch) {
    int bl = blockIdx.x;
    int b = bl / SEQ, l = bl % SEQ;
    int tid = threadIdx.x;
    __shared__ float sB[RRANK][NSTATE], sC[RRANK][NSTATE], scale[4];
    __shared__ float thl[NHEAD * NANG];
    const float* row = proj + (size_t)bl * DINP;
    if (tid < 128) {
        int r = tid / 64, n = tid % 64;
        sB[r][n] = row[COL_B + r * NSTATE + n];
    } else {
        int t2 = tid - 128;
        int r = t2 / 64, n = t2 % 64;
        sC[r][n] = row[COL_C + r * NSTATE + n];
    }
    for (int k = tid; k < NHEAD * NANG; k += 256)
        thl[k] = theta[(size_t)bl * NHEAD * NANG + k];
    __syncthreads();
    int g = tid / 64, lane = tid % 64;
    float v = (g < 2) ? sB[g][lane] : sC[g - 2][lane];
    float ss = v * v;
    #pragma unroll
    for (int off = 32; off; off >>= 1) ss += __shfl_xor(ss, off);
    if (lane == 0) scale[g] = rsqrtf(ss / NSTATE + EPSV);
    __syncthreads();
    float scB[2] = {scale[0], scale[1]};
    float scC[2] = {scale[2], scale[3]};
    for (int idx = tid; idx < RRANK * NHEAD * NSTATE; idx += 256) {
        int n = idx % NSTATE;
        int h = (idx / NSTATE) % NHEAD;
        int r = idx / (NSTATE * NHEAD);
        float outB, outC;
        if (n < HALFSPLIT) {
            int i = n >> 1;
            int n0 = i * 2, n1 = n0 + 1;
            float th = thl[h * NANG + i];
            float c = cosf(th), s = sinf(th);
            float b0 = sB[r][n0] * scB[r] * Bnw[n0] * Bbias[(h * RRANK + r) * NSTATE + n0];
            float b1 = sB[r][n1] * scB[r] * Bnw[n1] * Bbias[(h * RRANK + r) * NSTATE + n1];
            float c0 = sC[r][n0] * scC[r] * Cnw[n0] * Cbias[(h * RRANK + r) * NSTATE + n0];
            float c1 = sC[r][n1] * scC[r] * Cnw[n1] * Cbias[(h * RRANK + r) * NSTATE + n1];
            outB = (n & 1) ? (b0 * s + b1 * c) : (b0 * c - b1 * s);
            outC = (n & 1) ? (c0 * s + c1 * c) : (c0 * c - c1 * s);
        } else {
            outB = sB[r][n] * scB[r] * Bnw[n] * Bbias[(h * RRANK + r) * NSTATE + n];
            outC = sC[r][n] * scC[r] * Cnw[n] * Cbias[(h * RRANK + r) * NSTATE + n];
        }
        size_t o = ((size_t)((b * RRANK + r) * NHEAD + h) * SEQ + l) * NSTATE + n;
        Bh[o] = f2bf(outB);
        Ch[o] = f2bf(outC);
    }
}

// ---------------- att2: MFMA scan + fused combine/gate --------------------------
// block = (bh, tt); handles BOTH r with interleaved (independent) pipelines.
__global__ __launch_bounds__(256) void att2(const ushort* __restrict__ Bh,
        const ushort* __restrict__ Ch, const ushort* __restrict__ XT,
        const float* __restrict__ Pc, const float* __restrict__ DTv,
        const float* __restrict__ lamv, const float* __restrict__ proj,
        const float* __restrict__ mimo_x, const float* __restrict__ mimo_o,
        const float* __restrict__ Dvec, ushort* __restrict__ Yc) {
    const int bh = blockIdx.x, tt = blockIdx.y;
    const int b = bh / NHEAD, h = bh % NHEAD;
    const int tid = threadIdx.x, wv = tid >> 6, lane = tid & 63;
    __shared__ float Pl[SEQ], u1s[SEQ], u2s[SEQ];
    __shared__ ushort Pld[2][4][16][72];
    for (int t = tid; t < SEQ; t += 256) {
        Pl[t]  = Pc[bh * SEQ + t];
        u1s[t] = DTv[bh * SEQ + t] * lamv[bh * SEQ + t];
        u2s[t] = (t + 1 < SEQ) ? DTv[bh * SEQ + t + 1] * (1.f - lamv[bh * SEQ + t + 1]) : 0.f;
    }
    __syncthreads();
    const int r16 = lane & 15, kg = (lane >> 4) * 8;
    const int trow = tt * 64 + wv * 16;
    const int tr0 = trow + (lane >> 4) * 4;
    const int brh0 = (b * RRANK + 0) * NHEAD + h;
    const int brh1 = (b * RRANK + 1) * NHEAD + h;
    bf16x8 ca[2][2];
    {
        const ushort* cp0 = Ch + ((size_t)brh0 * SEQ + trow + r16) * NSTATE + kg;
        const ushort* cp1 = Ch + ((size_t)brh1 * SEQ + trow + r16) * NSTATE + kg;
        ca[0][0] = *(const bf16x8*)cp0;  ca[0][1] = *(const bf16x8*)(cp0 + 32);
        ca[1][0] = *(const bf16x8*)cp1;  ca[1][1] = *(const bf16x8*)(cp1 + 32);
    }
    f32x4 yacc[2][4];
    #pragma unroll
    for (int r2 = 0; r2 < 2; ++r2)
        #pragma unroll
        for (int pf = 0; pf < 4; ++pf) yacc[r2][pf] = (f32x4){0.f, 0.f, 0.f, 0.f};
    float Pt[4];
    #pragma unroll
    for (int r = 0; r < 4; ++r) Pt[r] = Pl[tr0 + r];
    float mmv[2][4];
    #pragma unroll
    for (int r2 = 0; r2 < 2; ++r2)
        #pragma unroll
        for (int pf = 0; pf < 4; ++pf) {
            int p = pf * 16 + r16;
            mmv[r2][pf] = mimo_x[(h * RRANK + r2) * HDIM + p] * mimo_o[(h * RRANK + r2) * HDIM + p];
        }
    const float Dh = Dvec[h];

    for (int jt = 0; jt <= tt; ++jt) {
        bf16x8 xf[4][2];
        #pragma unroll
        for (int pf = 0; pf < 4; ++pf) {
            const ushort* xp = XT + ((size_t)bh * HDIM + pf * 16 + r16) * SEQ + jt * 64 + kg;
            xf[pf][0] = *(const bf16x8*)xp;
            xf[pf][1] = *(const bf16x8*)(xp + 32);
        }
        // Gram + decay-weight for BOTH r (independent chains -> ILP)
        #pragma unroll
        for (int r2 = 0; r2 < 2; ++r2) {
            const size_t bbase = (size_t)(r2 ? brh1 : brh0) * SEQ;
            #pragma unroll
            for (int nf = 0; nf < 4; ++nf) {
                const ushort* bp = Bh + (bbase + jt * 64 + nf * 16 + r16) * NSTATE + kg;
                bf16x8 b0 = *(const bf16x8*)bp;
                bf16x8 b1 = *(const bf16x8*)(bp + 32);
                f32x4 g = (f32x4){0.f, 0.f, 0.f, 0.f};
                g = __builtin_amdgcn_mfma_f32_16x16x32_bf16(ca[r2][0], b0, g, 0, 0, 0);
                g = __builtin_amdgcn_mfma_f32_16x16x32_bf16(ca[r2][1], b1, g, 0, 0, 0);
                const int j = jt * 64 + nf * 16 + r16;
                const float Pj = Pl[j], v1 = u1s[j], v2 = u2s[j];
                #pragma unroll
                for (int r = 0; r < 4; ++r) {
                    const int t = tr0 + r;
                    float wgt = 0.f;
                    if (j <= t) wgt = expf(Pt[r] - Pj) * (v1 + ((j < t) ? v2 : 0.f));
                    Pld[r2][wv][(lane >> 4) * 4 + r][nf * 16 + r16] = f2bf(g[r] * wgt);
                }
            }
        }
        // PV for BOTH r
        #pragma unroll
        for (int r2 = 0; r2 < 2; ++r2) {
            bf16x8 pa0 = *(const bf16x8*)&Pld[r2][wv][r16][kg];
            bf16x8 pa1 = *(const bf16x8*)&Pld[r2][wv][r16][32 + kg];
            #pragma unroll
            for (int pf = 0; pf < 4; ++pf) {
                yacc[r2][pf] = __builtin_amdgcn_mfma_f32_16x16x32_bf16(pa0, xf[pf][0], yacc[r2][pf], 0, 0, 0);
                yacc[r2][pf] = __builtin_amdgcn_mfma_f32_16x16x32_bf16(pa1, xf[pf][1], yacc[r2][pf], 0, 0, 0);
            }
        }
    }
    // fused combine: y = y0*mm0 + y1*mm1 + D*x, gated by silu(z), -> bf16 Yc
    #pragma unroll
    for (int pf = 0; pf < 4; ++pf) {
        const int p = pf * 16 + r16;
        #pragma unroll
        for (int r = 0; r < 4; ++r) {
            const int t = tr0 + r;
            const float* rowp = proj + (size_t)(b * SEQ + t) * DINP;
            float xv = rowp[COL_X + h * HDIM + p];
            float zv = rowp[COL_Z + h * HDIM + p];
            float y = yacc[0][pf][r] * mmv[0][pf] + yacc[1][pf][r] * mmv[1][pf] + Dh * xv;
            y *= zv * sigmoidf_(zv);
            Yc[(size_t)(b * SEQ + t) * DIEXP + h * HDIM + p] = f2bf(y);
        }
    }
}

// ---------------- launch ----------------
extern "C" void kernel_launch(void* const* d_in, const int* in_sizes, int n_in,
                              void* d_out, int out_size, void* d_ws, size_t ws_size,
                              hipStream_t stream) {
    const float* u        = (const float*)d_in[0];
    const float* in_w     = (const float*)d_in[1];
    const float* dt_bias  = (const float*)d_in[2];
    const float* B_bias   = (const float*)d_in[3];
    const float* C_bias   = (const float*)d_in[4];
    const float* B_norm_w = (const float*)d_in[5];
    const float* C_norm_w = (const float*)d_in[6];
    const float* mimo_x   = (const float*)d_in[7];
    const float* mimo_o   = (const float*)d_in[8];
    const float* Dvec     = (const float*)d_in[9];
    const float* out_w    = (const float*)d_in[10];
    float* out = (float*)d_out;

    float* ws = (float*)d_ws;
    float*  proj  = ws;                           // 1,748,992 f
    float*  DTA   = proj + 1748992;               // 65,536 f (128 x 512)
    ushort* Bh_bf = (ushort*)(DTA + 65536);       // 786,432 f
    ushort* Ch_bf = (ushort*)(DTA + 851968);      // 786,432 f
    ushort* XT_bf = (ushort*)(DTA + 1638400);     // 393,216 f
    float*  theta = DTA + 2031616;                // 196,608 f
    float*  Pc    = DTA + 2228224;                // 12,288 f
    float*  DTv   = DTA + 2240512;                // 12,288 f
    float*  lamv  = DTA + 2252800;                // 12,288 f
    ushort* Yc_bf = (ushort*)(DTA + 2265088);     // 393,216 f
    float*  Part  = DTA + 2658304;                // 1,572,864 f (4 x 512 x 768)

    // 1) proj = u @ in_proj_w^T (+ transposed DTA strip); 432 blocks
    gemm1<<<dim3(DINP_PAD / 64, 8), 256, 0, stream>>>(u, in_w, proj, DTA);
    // 2) scalars + cumsums + tiled x-transpose
    scan_kernel<<<BATCH * NHEAD, 256, 0, stream>>>(DTA, proj, dt_bias, DTv, lamv,
                                                   Pc, theta, XT_bf);
    // 3) RMS + bias + RoPE -> bf16 Bh/Ch
    prep3<<<BATCH * SEQ, 256, 0, stream>>>(proj, B_bias, C_bias, B_norm_w, C_norm_w,
                                           theta, Bh_bf, Ch_bf);
    // 4) MFMA scan + fused combine -> bf16 Yc
    att2<<<dim3(BATCH * NHEAD, 4), 256, 0, stream>>>(Bh_bf, Ch_bf, XT_bf, Pc, DTv,
                                                     lamv, proj, mimo_x, mimo_o,
                                                     Dvec, Yc_bf);
    // 5) split-K GEMM2 partials; 384 blocks
    gemm2<<<dim3(DMODL / 64, 8, 4), 256, 0, stream>>>(Yc_bf, out_w, Part);
    // 6) out = sum of 4 partials
    reduce4<<<384, 256, 0, stream>>>(Part, out);
}

// Round 9
// 76.813 us; speedup vs baseline: 1.2911x; 1.0885x over previous
//
#include <hip/hip_runtime.h>
#include <hip/hip_bf16.h>
#include <math.h>

typedef __bf16 bf16x8 __attribute__((ext_vector_type(8)));
typedef float  f32x4  __attribute__((ext_vector_type(4)));

// ---------------- problem constants ----------------
#define BATCH 2
#define SEQ   256
#define DMODL 768
#define DIEXP 1536
#define NHEAD 24
#define HDIM  64
#define NSTATE 64
#define RRANK 2
#define NANG  16
#define HALFSPLIT 32
#define DINP  3416
#define DINP_PAD 3456     // 54*64
#define AFLOOR 1e-4f
#define EPSV   1e-5f

#define COL_Z    0
#define COL_X    1536
#define COL_B    3072
#define COL_C    3200
#define COL_DT   3328     // DTA strip starts here: DTA[c-3328][row]
#define COL_A    3352
#define COL_TRAP 3376
#define COL_ANG  3400

__device__ __forceinline__ float softplusf(float x) {
    if (x > 20.f) return x;
    return log1pf(expf(x));
}
__device__ __forceinline__ float sigmoidf_(float x) {
    return 1.f / (1.f + __expf(-x));
}
__device__ __forceinline__ ushort f2bf(float f) {
    uint u = __float_as_uint(f);
    uint r = (u + 0x7FFFu + ((u >> 16) & 1u)) >> 16;
    return (ushort)r;
}

// ---------------- GEMM1: proj = u @ in_w^T (fp32 in, fused bf16 staging) -------
// BM=64, BN=64, BK=64 -> 54x8 = 432 blocks. 4 waves (2x2), wave = 32x32.
// XOR-swizzled double-buffered LDS. Side-writes transposed scalar strip to DTA.
__global__ __launch_bounds__(256) void gemm1(const float* __restrict__ A,
        const float* __restrict__ W, float* __restrict__ C, float* __restrict__ DTA) {
    const int bm = blockIdx.y * 64, bn = blockIdx.x * 64;
    const int tid = threadIdx.x;
    const int wv = tid >> 6, lane = tid & 63;
    const int wr = (wv >> 1) * 32, wc = (wv & 1) * 32;
    __shared__ ushort As[2][64 * 64];
    __shared__ ushort Bs[2][64 * 64];
    const int srow = tid >> 4, sc4 = tid & 15;
    const int NT = DMODL >> 6;   // 12
    float4 ra[4], rw[4];

    auto load_tile = [&](int t) {
        const int k0 = t * 64;
        #pragma unroll
        for (int p = 0; p < 4; ++p)
            ra[p] = *(const float4*)(A + (size_t)(bm + p * 16 + srow) * DMODL + k0 + sc4 * 4);
        #pragma unroll
        for (int p = 0; p < 4; ++p) {
            int r = p * 16 + srow;
            rw[p] = (bn + r < DINP)
                  ? *(const float4*)(W + (size_t)(bn + r) * DMODL + k0 + sc4 * 4)
                  : (float4){0.f, 0.f, 0.f, 0.f};
        }
    };
    auto write_tile = [&](int buf) {
        #pragma unroll
        for (int p = 0; p < 4; ++p) {
            int r = p * 16 + srow;
            int byt = (sc4 * 8) ^ ((r & 7) << 4);
            ushort4 h;
            h.x = f2bf(ra[p].x); h.y = f2bf(ra[p].y);
            h.z = f2bf(ra[p].z); h.w = f2bf(ra[p].w);
            *(ushort4*)(&As[buf][r * 64 + (byt >> 1)]) = h;
        }
        #pragma unroll
        for (int p = 0; p < 4; ++p) {
            int r = p * 16 + srow;
            int byt = (sc4 * 8) ^ ((r & 7) << 4);
            ushort4 h;
            h.x = f2bf(rw[p].x); h.y = f2bf(rw[p].y);
            h.z = f2bf(rw[p].z); h.w = f2bf(rw[p].w);
            *(ushort4*)(&Bs[buf][r * 64 + (byt >> 1)]) = h;
        }
    };

    f32x4 acc[2][2];
    #pragma unroll
    for (int m = 0; m < 2; ++m)
        #pragma unroll
        for (int n = 0; n < 2; ++n) acc[m][n] = (f32x4){0.f, 0.f, 0.f, 0.f};
    const int fr = lane & 15, fk = (lane >> 4) * 16;

    auto compute = [&](int buf) {
        #pragma unroll
        for (int kk = 0; kk < 2; ++kk) {
            bf16x8 af[2], bff[2];
            #pragma unroll
            for (int m = 0; m < 2; ++m) {
                int r = wr + m * 16 + fr;
                int byt = (kk * 64 + fk) ^ ((r & 7) << 4);
                af[m] = *(const bf16x8*)(&As[buf][r * 64 + (byt >> 1)]);
            }
            #pragma unroll
            for (int n = 0; n < 2; ++n) {
                int r = wc + n * 16 + fr;
                int byt = (kk * 64 + fk) ^ ((r & 7) << 4);
                bff[n] = *(const bf16x8*)(&Bs[buf][r * 64 + (byt >> 1)]);
            }
            #pragma unroll
            for (int m = 0; m < 2; ++m)
                #pragma unroll
                for (int n = 0; n < 2; ++n)
                    acc[m][n] = __builtin_amdgcn_mfma_f32_16x16x32_bf16(af[m], bff[n], acc[m][n], 0, 0, 0);
        }
    };

    load_tile(0);
    write_tile(0);
    __syncthreads();
    for (int t = 0; t < NT; ++t) {
        if (t + 1 < NT) load_tile(t + 1);
        compute(t & 1);
        if (t + 1 < NT) write_tile((t + 1) & 1);
        __syncthreads();
    }

    const int r0 = bm + wr + (lane >> 4) * 4;
    #pragma unroll
    for (int n = 0; n < 2; ++n) {
        int col = bn + wc + n * 16 + fr;
        if (col >= 3328) {   // transposed side-strip for scan's coalesced reads
            #pragma unroll
            for (int m = 0; m < 2; ++m)
                #pragma unroll
                for (int r = 0; r < 4; ++r)
                    DTA[(size_t)(col - 3328) * 512 + r0 + m * 16 + r] = acc[m][n][r];
        }
        if (col >= DINP) continue;
        #pragma unroll
        for (int m = 0; m < 2; ++m)
            #pragma unroll
            for (int r = 0; r < 4; ++r)
                C[(size_t)(r0 + m * 16 + r) * DINP + col] = acc[m][n][r];
    }
}

// ---------------- GEMM2 split-K: Part[s] = Yc(bf16) @ out_w^T over K-slice s ----
__global__ __launch_bounds__(256) void gemm2(const ushort* __restrict__ A,
        const float* __restrict__ W, float* __restrict__ Part) {
    const int bm = blockIdx.y * 64, bn = blockIdx.x * 64, ks = blockIdx.z;
    const int kbase = ks * 384;
    const int tid = threadIdx.x;
    const int wv = tid >> 6, lane = tid & 63;
    const int wr = (wv >> 1) * 32, wc = (wv & 1) * 32;
    __shared__ ushort As[2][64 * 64];
    __shared__ ushort Bs[2][64 * 64];
    const int srow = tid >> 4, sc4 = tid & 15;
    const int arow = tid >> 3, acol = (tid & 7) * 8;
    const int NT = 6;
    uint4 ra[2];
    float4 rw[4];

    auto load_tile = [&](int t) {
        const int k0 = kbase + t * 64;
        #pragma unroll
        for (int p = 0; p < 2; ++p)
            ra[p] = *(const uint4*)(A + (size_t)(bm + p * 32 + arow) * DIEXP + k0 + acol);
        #pragma unroll
        for (int p = 0; p < 4; ++p)
            rw[p] = *(const float4*)(W + (size_t)(bn + p * 16 + srow) * DIEXP + k0 + sc4 * 4);
    };
    auto write_tile = [&](int buf) {
        #pragma unroll
        for (int p = 0; p < 2; ++p) {
            int r = p * 32 + arow;
            int byt = (acol * 2) ^ ((r & 7) << 4);
            *(uint4*)(&As[buf][r * 64 + (byt >> 1)]) = ra[p];
        }
        #pragma unroll
        for (int p = 0; p < 4; ++p) {
            int r = p * 16 + srow;
            int byt = (sc4 * 8) ^ ((r & 7) << 4);
            ushort4 h;
            h.x = f2bf(rw[p].x); h.y = f2bf(rw[p].y);
            h.z = f2bf(rw[p].z); h.w = f2bf(rw[p].w);
            *(ushort4*)(&Bs[buf][r * 64 + (byt >> 1)]) = h;
        }
    };

    f32x4 acc[2][2];
    #pragma unroll
    for (int m = 0; m < 2; ++m)
        #pragma unroll
        for (int n = 0; n < 2; ++n) acc[m][n] = (f32x4){0.f, 0.f, 0.f, 0.f};
    const int fr = lane & 15, fk = (lane >> 4) * 16;

    auto compute = [&](int buf) {
        #pragma unroll
        for (int kk = 0; kk < 2; ++kk) {
            bf16x8 af[2], bff[2];
            #pragma unroll
            for (int m = 0; m < 2; ++m) {
                int r = wr + m * 16 + fr;
                int byt = (kk * 64 + fk) ^ ((r & 7) << 4);
                af[m] = *(const bf16x8*)(&As[buf][r * 64 + (byt >> 1)]);
            }
            #pragma unroll
            for (int n = 0; n < 2; ++n) {
                int r = wc + n * 16 + fr;
                int byt = (kk * 64 + fk) ^ ((r & 7) << 4);
                bff[n] = *(const bf16x8*)(&Bs[buf][r * 64 + (byt >> 1)]);
            }
            #pragma unroll
            for (int m = 0; m < 2; ++m)
                #pragma unroll
                for (int n = 0; n < 2; ++n)
                    acc[m][n] = __builtin_amdgcn_mfma_f32_16x16x32_bf16(af[m], bff[n], acc[m][n], 0, 0, 0);
        }
    };

    load_tile(0);
    write_tile(0);
    __syncthreads();
    for (int t = 0; t < NT; ++t) {
        if (t + 1 < NT) load_tile(t + 1);
        compute(t & 1);
        if (t + 1 < NT) write_tile((t + 1) & 1);
        __syncthreads();
    }

    const int r0 = bm + wr + (lane >> 4) * 4;
    float* P = Part + (size_t)ks * 512 * DMODL;
    #pragma unroll
    for (int n = 0; n < 2; ++n) {
        int col = bn + wc + n * 16 + fr;
        #pragma unroll
        for (int m = 0; m < 2; ++m)
            #pragma unroll
            for (int r = 0; r < 4; ++r)
                P[(size_t)(r0 + m * 16 + r) * DMODL + col] = acc[m][n][r];
    }
}

// ---------------- reduce4: out = sum_s Part[s] ----------------------------------
__global__ void reduce4(const float* __restrict__ Part, float* __restrict__ out) {
    const int i = blockIdx.x * 256 + threadIdx.x;   // float4 index, 98304 total
    const float4* p4 = (const float4*)Part;
    float4 a = p4[i];
    float4 b = p4[i + 98304];
    float4 c = p4[i + 196608];
    float4 d = p4[i + 294912];
    float4 r;
    r.x = a.x + b.x + c.x + d.x;
    r.y = a.y + b.y + c.y + d.y;
    r.z = a.z + b.z + c.z + d.z;
    r.w = a.w + b.w + c.w + d.w;
    ((float4*)out)[i] = r;
}

// ---------------- scan: scalars + cumsums + tiled x-transpose (per b,h) --------
__global__ __launch_bounds__(256) void scan_kernel(const float* __restrict__ DTA,
        const float* __restrict__ proj, const float* __restrict__ dt_bias,
        float* __restrict__ DTv, float* __restrict__ lamv, float* __restrict__ Pc,
        float* __restrict__ theta, ushort* __restrict__ XT) {
    const int bh = blockIdx.x;
    const int b = bh / NHEAD, h = bh % NHEAD;
    const int tid = threadIdx.x;
    __shared__ float mm[SEQ][18];
    __shared__ ushort tile[64][66];
    const int l = tid;
    const int gl = b * SEQ + l;
    float DT  = softplusf(DTA[(size_t)h * 512 + gl] + dt_bias[h]);
    float Asp = fmaxf(softplusf(DTA[(size_t)(24 + h) * 512 + gl]), AFLOOR);
    float la  = -Asp * DT;
    float lam = sigmoidf_(DTA[(size_t)(48 + h) * 512 + gl]);
    DTv[bh * SEQ + l] = DT;
    lamv[bh * SEQ + l] = lam;
    #pragma unroll
    for (int i = 0; i < NANG; ++i) mm[l][i] = DT * DTA[(size_t)(72 + i) * 512 + gl];
    mm[l][16] = la;
    __syncthreads();
    const int wv = tid >> 6, lane = tid & 63;
    for (int ch = wv; ch < 17; ch += 4) {
        float carry = 0.f;
        for (int seg = 0; seg < 4; ++seg) {
            float v = mm[seg * 64 + lane][ch];
            #pragma unroll
            for (int off = 1; off < 64; off <<= 1) {
                float t = __shfl_up(v, off);
                if (lane >= off) v += t;
            }
            v += carry;
            carry = __shfl(v, 63);
            int ll = seg * 64 + lane;
            if (ch < 16)
                theta[((size_t)(b * SEQ + ll) * NHEAD + h) * NANG + ch] = v;
            else
                Pc[bh * SEQ + ll] = v;
        }
    }
    // tiled x-transpose: XT[(bh*64+p)*SEQ + l] = bf16(x[b,l,h,p]) (coalesced both sides)
    for (int jt = 0; jt < 4; ++jt) {
        __syncthreads();
        for (int i = tid; i < 4096; i += 256) {
            int j = i >> 6, p = i & 63;
            tile[j][p] = f2bf(proj[(size_t)(b * SEQ + jt * 64 + j) * DINP + COL_X + h * HDIM + p]);
        }
        __syncthreads();
        for (int i = tid; i < 4096; i += 256) {
            int p = i >> 6, j = i & 63;
            XT[((size_t)bh * HDIM + p) * SEQ + jt * 64 + j] = tile[j][p];
        }
    }
}

// ---------------- prep3: RMS-norm + bias + RoPE -> bf16 Bh, Ch ------------------
__global__ __launch_bounds__(256) void prep3(const float* __restrict__ proj,
        const float* __restrict__ Bbias, const float* __restrict__ Cbias,
        const float* __restrict__ Bnw, const float* __restrict__ Cnw,
        const float* __restrict__ theta,
        ushort* __restrict__ Bh, ushort* __restrict__ Ch) {
    int bl = blockIdx.x;
    int b = bl / SEQ, l = bl % SEQ;
    int tid = threadIdx.x;
    __shared__ float sB[RRANK][NSTATE], sC[RRANK][NSTATE], scale[4];
    __shared__ float thl[NHEAD * NANG];
    const float* row = proj + (size_t)bl * DINP;
    if (tid < 128) {
        int r = tid / 64, n = tid % 64;
        sB[r][n] = row[COL_B + r * NSTATE + n];
    } else {
        int t2 = tid - 128;
        int r = t2 / 64, n = t2 % 64;
        sC[r][n] = row[COL_C + r * NSTATE + n];
    }
    for (int k = tid; k < NHEAD * NANG; k += 256)
        thl[k] = theta[(size_t)bl * NHEAD * NANG + k];
    __syncthreads();
    int g = tid / 64, lane = tid % 64;
    float v = (g < 2) ? sB[g][lane] : sC[g - 2][lane];
    float ss = v * v;
    #pragma unroll
    for (int off = 32; off; off >>= 1) ss += __shfl_xor(ss, off);
    if (lane == 0) scale[g] = rsqrtf(ss / NSTATE + EPSV);
    __syncthreads();
    float scB[2] = {scale[0], scale[1]};
    float scC[2] = {scale[2], scale[3]};
    for (int idx = tid; idx < RRANK * NHEAD * NSTATE; idx += 256) {
        int n = idx % NSTATE;
        int h = (idx / NSTATE) % NHEAD;
        int r = idx / (NSTATE * NHEAD);
        float outB, outC;
        if (n < HALFSPLIT) {
            int i = n >> 1;
            int n0 = i * 2, n1 = n0 + 1;
            float th = thl[h * NANG + i];
            float c = cosf(th), s = sinf(th);
            float b0 = sB[r][n0] * scB[r] * Bnw[n0] * Bbias[(h * RRANK + r) * NSTATE + n0];
            float b1 = sB[r][n1] * scB[r] * Bnw[n1] * Bbias[(h * RRANK + r) * NSTATE + n1];
            float c0 = sC[r][n0] * scC[r] * Cnw[n0] * Cbias[(h * RRANK + r) * NSTATE + n0];
            float c1 = sC[r][n1] * scC[r] * Cnw[n1] * Cbias[(h * RRANK + r) * NSTATE + n1];
            outB = (n & 1) ? (b0 * s + b1 * c) : (b0 * c - b1 * s);
            outC = (n & 1) ? (c0 * s + c1 * c) : (c0 * c - c1 * s);
        } else {
            outB = sB[r][n] * scB[r] * Bnw[n] * Bbias[(h * RRANK + r) * NSTATE + n];
            outC = sC[r][n] * scC[r] * Cnw[n] * Cbias[(h * RRANK + r) * NSTATE + n];
        }
        size_t o = ((size_t)((b * RRANK + r) * NHEAD + h) * SEQ + l) * NSTATE + n;
        Bh[o] = f2bf(outB);
        Ch[o] = f2bf(outC);
    }
}

// ---------------- att2: MFMA scan + fused combine/gate --------------------------
// block = (bh, tt). Per jt: both r2 Grams (MFMA back-to-back), SHARED decay
// weight table w[nf][r] once with __expf (r2-independent), Pld writes, then
// 16 back-to-back PV MFMAs. Math identical to round-5 version.
__global__ __launch_bounds__(256) void att2(const ushort* __restrict__ Bh,
        const ushort* __restrict__ Ch, const ushort* __restrict__ XT,
        const float* __restrict__ Pc, const float* __restrict__ DTv,
        const float* __restrict__ lamv, const float* __restrict__ proj,
        const float* __restrict__ mimo_x, const float* __restrict__ mimo_o,
        const float* __restrict__ Dvec, ushort* __restrict__ Yc) {
    const int bh = blockIdx.x, tt = blockIdx.y;
    const int b = bh / NHEAD, h = bh % NHEAD;
    const int tid = threadIdx.x, wv = tid >> 6, lane = tid & 63;
    __shared__ float Pl[SEQ], u1s[SEQ], u2s[SEQ];
    __shared__ ushort Pld[2][4][16][72];
    for (int t = tid; t < SEQ; t += 256) {
        Pl[t]  = Pc[bh * SEQ + t];
        u1s[t] = DTv[bh * SEQ + t] * lamv[bh * SEQ + t];
        u2s[t] = (t + 1 < SEQ) ? DTv[bh * SEQ + t + 1] * (1.f - lamv[bh * SEQ + t + 1]) : 0.f;
    }
    __syncthreads();
    const int r16 = lane & 15, kg = (lane >> 4) * 8;
    const int trow = tt * 64 + wv * 16;
    const int tr0 = trow + (lane >> 4) * 4;
    const int brh0 = (b * RRANK + 0) * NHEAD + h;
    const int brh1 = (b * RRANK + 1) * NHEAD + h;
    bf16x8 ca[2][2];
    {
        const ushort* cp0 = Ch + ((size_t)brh0 * SEQ + trow + r16) * NSTATE + kg;
        const ushort* cp1 = Ch + ((size_t)brh1 * SEQ + trow + r16) * NSTATE + kg;
        ca[0][0] = *(const bf16x8*)cp0;  ca[0][1] = *(const bf16x8*)(cp0 + 32);
        ca[1][0] = *(const bf16x8*)cp1;  ca[1][1] = *(const bf16x8*)(cp1 + 32);
    }
    f32x4 yacc[2][4];
    #pragma unroll
    for (int r2 = 0; r2 < 2; ++r2)
        #pragma unroll
        for (int pf = 0; pf < 4; ++pf) yacc[r2][pf] = (f32x4){0.f, 0.f, 0.f, 0.f};
    float Pt[4];
    #pragma unroll
    for (int r = 0; r < 4; ++r) Pt[r] = Pl[tr0 + r];
    const float Dh = Dvec[h];

    for (int jt = 0; jt <= tt; ++jt) {
        // PV operand tiles (L2-resident)
        bf16x8 xf[4][2];
        #pragma unroll
        for (int pf = 0; pf < 4; ++pf) {
            const ushort* xp = XT + ((size_t)bh * HDIM + pf * 16 + r16) * SEQ + jt * 64 + kg;
            xf[pf][0] = *(const bf16x8*)xp;
            xf[pf][1] = *(const bf16x8*)(xp + 32);
        }
        // Grams for both r2 (independent MFMA chains, issued back-to-back)
        f32x4 g[2][4];
        #pragma unroll
        for (int r2 = 0; r2 < 2; ++r2) {
            const size_t bbase = (size_t)(r2 ? brh1 : brh0) * SEQ;
            #pragma unroll
            for (int nf = 0; nf < 4; ++nf) {
                const ushort* bp = Bh + (bbase + jt * 64 + nf * 16 + r16) * NSTATE + kg;
                bf16x8 b0 = *(const bf16x8*)bp;
                bf16x8 b1 = *(const bf16x8*)(bp + 32);
                f32x4 gg = (f32x4){0.f, 0.f, 0.f, 0.f};
                gg = __builtin_amdgcn_mfma_f32_16x16x32_bf16(ca[r2][0], b0, gg, 0, 0, 0);
                gg = __builtin_amdgcn_mfma_f32_16x16x32_bf16(ca[r2][1], b1, gg, 0, 0, 0);
                g[r2][nf] = gg;
            }
        }
        // SHARED decay weights (r2-independent; VALU fills the MFMA shadow)
        float w[4][4];
        #pragma unroll
        for (int nf = 0; nf < 4; ++nf) {
            const int j = jt * 64 + nf * 16 + r16;
            const float Pj = Pl[j], v1 = u1s[j], v2 = u2s[j];
            #pragma unroll
            for (int r = 0; r < 4; ++r) {
                const int t = tr0 + r;
                w[nf][r] = (j <= t) ? __expf(Pt[r] - Pj) * (v1 + ((j < t) ? v2 : 0.f)) : 0.f;
            }
        }
        // combine -> Pld (bf16 A-fragment layout)
        #pragma unroll
        for (int r2 = 0; r2 < 2; ++r2)
            #pragma unroll
            for (int nf = 0; nf < 4; ++nf)
                #pragma unroll
                for (int r = 0; r < 4; ++r)
                    Pld[r2][wv][(lane >> 4) * 4 + r][nf * 16 + r16] = f2bf(g[r2][nf][r] * w[nf][r]);
        // PV (16 back-to-back MFMAs)
        #pragma unroll
        for (int r2 = 0; r2 < 2; ++r2) {
            bf16x8 pa0 = *(const bf16x8*)&Pld[r2][wv][r16][kg];
            bf16x8 pa1 = *(const bf16x8*)&Pld[r2][wv][r16][32 + kg];
            #pragma unroll
            for (int pf = 0; pf < 4; ++pf) {
                yacc[r2][pf] = __builtin_amdgcn_mfma_f32_16x16x32_bf16(pa0, xf[pf][0], yacc[r2][pf], 0, 0, 0);
                yacc[r2][pf] = __builtin_amdgcn_mfma_f32_16x16x32_bf16(pa1, xf[pf][1], yacc[r2][pf], 0, 0, 0);
            }
        }
    }
    // fused combine: y = y0*mm0 + y1*mm1 + D*x, gated by silu(z), -> bf16 Yc
    #pragma unroll
    for (int pf = 0; pf < 4; ++pf) {
        const int p = pf * 16 + r16;
        const float mm0 = mimo_x[(h * RRANK + 0) * HDIM + p] * mimo_o[(h * RRANK + 0) * HDIM + p];
        const float mm1 = mimo_x[(h * RRANK + 1) * HDIM + p] * mimo_o[(h * RRANK + 1) * HDIM + p];
        #pragma unroll
        for (int r = 0; r < 4; ++r) {
            const int t = tr0 + r;
            const float* rowp = proj + (size_t)(b * SEQ + t) * DINP;
            float xv = rowp[COL_X + h * HDIM + p];
            float zv = rowp[COL_Z + h * HDIM + p];
            float y = yacc[0][pf][r] * mm0 + yacc[1][pf][r] * mm1 + Dh * xv;
            y *= zv * sigmoidf_(zv);
            Yc[(size_t)(b * SEQ + t) * DIEXP + h * HDIM + p] = f2bf(y);
        }
    }
}

// ---------------- launch ----------------
extern "C" void kernel_launch(void* const* d_in, const int* in_sizes, int n_in,
                              void* d_out, int out_size, void* d_ws, size_t ws_size,
                              hipStream_t stream) {
    const float* u        = (const float*)d_in[0];
    const float* in_w     = (const float*)d_in[1];
    const float* dt_bias  = (const float*)d_in[2];
    const float* B_bias   = (const float*)d_in[3];
    const float* C_bias   = (const float*)d_in[4];
    const float* B_norm_w = (const float*)d_in[5];
    const float* C_norm_w = (const float*)d_in[6];
    const float* mimo_x   = (const float*)d_in[7];
    const float* mimo_o   = (const float*)d_in[8];
    const float* Dvec     = (const float*)d_in[9];
    const float* out_w    = (const float*)d_in[10];
    float* out = (float*)d_out;

    // workspace layout — round-5 verified strides.
    // NOTE: Bh/Ch are 96 (b,r,h) x 256 x 64 = 1,572,864 bf16 = 786,432 FLOATS each.
    float* ws = (float*)d_ws;
    float*  proj  = ws;                           // 1,748,992 f
    float*  DTA   = proj + 1748992;               // 65,536 f (128 x 512)
    ushort* Bh_bf = (ushort*)(DTA + 65536);       // 1,572,864 us = 786,432 f
    ushort* Ch_bf = (ushort*)(DTA + 851968);      // 1,572,864 us = 786,432 f
    ushort* XT_bf = (ushort*)(DTA + 1638400);     // 786,432 us   = 393,216 f
    float*  theta = DTA + 2031616;                // 196,608 f
    float*  Pc    = DTA + 2228224;                // 12,288 f
    float*  DTv   = DTA + 2240512;                // 12,288 f
    float*  lamv  = DTA + 2252800;                // 12,288 f
    ushort* Yc_bf = (ushort*)(DTA + 2265088);     // 786,432 us   = 393,216 f
    float*  Part  = DTA + 2658304;                // 1,572,864 f  -> total ~23.9 MB

    // 1) proj = u @ in_proj_w^T (+ transposed DTA strip); 432 blocks
    gemm1<<<dim3(DINP_PAD / 64, 8), 256, 0, stream>>>(u, in_w, proj, DTA);
    // 2) scalars + cumsums + tiled x-transpose
    scan_kernel<<<BATCH * NHEAD, 256, 0, stream>>>(DTA, proj, dt_bias, DTv, lamv,
                                                   Pc, theta, XT_bf);
    // 3) RMS + bias + RoPE -> bf16 Bh/Ch
    prep3<<<BATCH * SEQ, 256, 0, stream>>>(proj, B_bias, C_bias, B_norm_w, C_norm_w,
                                           theta, Bh_bf, Ch_bf);
    // 4) MFMA scan + fused combine -> bf16 Yc
    att2<<<dim3(BATCH * NHEAD, 4), 256, 0, stream>>>(Bh_bf, Ch_bf, XT_bf, Pc, DTv,
                                                     lamv, proj, mimo_x, mimo_o,
                                                     Dvec, Yc_bf);
    // 5) split-K GEMM2 partials; 384 blocks
    gemm2<<<dim3(DMODL / 64, 8, 4), 256, 0, stream>>>(Yc_bf, out_w, Part);
    // 6) out = sum of 4 partials
    reduce4<<<384, 256, 0, stream>>>(Part, out);
}

// Round 10
// 66.342 us; speedup vs baseline: 1.4949x; 1.1578x over previous
//
#include <hip/hip_runtime.h>
#include <hip/hip_bf16.h>
#include <math.h>

typedef __bf16 bf16x8 __attribute__((ext_vector_type(8)));
typedef float  f32x4  __attribute__((ext_vector_type(4)));

// ---------------- problem constants ----------------
#define BATCH 2
#define SEQ   256
#define DMODL 768
#define DIEXP 1536
#define NHEAD 24
#define HDIM  64
#define NSTATE 64
#define RRANK 2
#define NANG  16
#define HALFSPLIT 32
#define DINP  3416
#define DINP_PAD 3456     // 54*64
#define AFLOOR 1e-4f
#define EPSV   1e-5f

__device__ __forceinline__ float softplusf(float x) {
    if (x > 20.f) return x;
    return log1pf(expf(x));
}
__device__ __forceinline__ float sigmoidf_(float x) {
    return 1.f / (1.f + __expf(-x));
}
__device__ __forceinline__ ushort f2bf(float f) {
    uint u = __float_as_uint(f);
    uint r = (u + 0x7FFFu + ((u >> 16) & 1u)) >> 16;
    return (ushort)r;
}
__device__ __forceinline__ float bf2f(ushort x) {
    uint u = ((uint)x) << 16;
    return __uint_as_float(u);
}

// ---------------- GEMM1: [z|x|B|C|scalars] = u @ in_w^T, routed epilogue --------
// BM=64, BN=64, BK=64 -> 432 blocks. fp32 operands -> bf16 in LDS staging.
// Epilogue routes by column block (bn is block-uniform):
//   bn in [0,1536)    -> ZT  bf16 [(b*24+h)*64+p][t]   (via LDS transpose)
//   bn in [1536,3072) -> XT  bf16 [(b*24+h)*64+p][t]   (via LDS transpose)
//   bn in [3072,3328) -> BC  bf16 [row][256] row-major
//   bn in [3328,3456) -> DTA fp32 transposed [c-3328][row]
__global__ __launch_bounds__(256) void gemm1(const float* __restrict__ A,
        const float* __restrict__ W, ushort* __restrict__ ZT, ushort* __restrict__ XT,
        ushort* __restrict__ BC, float* __restrict__ DTA) {
    const int bm = blockIdx.y * 64, bn = blockIdx.x * 64;
    const int tid = threadIdx.x;
    const int wv = tid >> 6, lane = tid & 63;
    const int wr = (wv >> 1) * 32, wc = (wv & 1) * 32;
    __shared__ ushort As[2][64 * 64];
    __shared__ ushort Bs[2][64 * 64];
    __shared__ ushort Ts[64][72];
    const int srow = tid >> 4, sc4 = tid & 15;
    const int NT = DMODL >> 6;   // 12
    float4 ra[4], rw[4];

    auto load_tile = [&](int t) {
        const int k0 = t * 64;
        #pragma unroll
        for (int p = 0; p < 4; ++p)
            ra[p] = *(const float4*)(A + (size_t)(bm + p * 16 + srow) * DMODL + k0 + sc4 * 4);
        #pragma unroll
        for (int p = 0; p < 4; ++p) {
            int r = p * 16 + srow;
            rw[p] = (bn + r < DINP)
                  ? *(const float4*)(W + (size_t)(bn + r) * DMODL + k0 + sc4 * 4)
                  : (float4){0.f, 0.f, 0.f, 0.f};
        }
    };
    auto write_tile = [&](int buf) {
        #pragma unroll
        for (int p = 0; p < 4; ++p) {
            int r = p * 16 + srow;
            int byt = (sc4 * 8) ^ ((r & 7) << 4);
            ushort4 h;
            h.x = f2bf(ra[p].x); h.y = f2bf(ra[p].y);
            h.z = f2bf(ra[p].z); h.w = f2bf(ra[p].w);
            *(ushort4*)(&As[buf][r * 64 + (byt >> 1)]) = h;
        }
        #pragma unroll
        for (int p = 0; p < 4; ++p) {
            int r = p * 16 + srow;
            int byt = (sc4 * 8) ^ ((r & 7) << 4);
            ushort4 h;
            h.x = f2bf(rw[p].x); h.y = f2bf(rw[p].y);
            h.z = f2bf(rw[p].z); h.w = f2bf(rw[p].w);
            *(ushort4*)(&Bs[buf][r * 64 + (byt >> 1)]) = h;
        }
    };

    f32x4 acc[2][2];
    #pragma unroll
    for (int m = 0; m < 2; ++m)
        #pragma unroll
        for (int n = 0; n < 2; ++n) acc[m][n] = (f32x4){0.f, 0.f, 0.f, 0.f};
    const int fr = lane & 15, fk = (lane >> 4) * 16;

    auto compute = [&](int buf) {
        #pragma unroll
        for (int kk = 0; kk < 2; ++kk) {
            bf16x8 af[2], bff[2];
            #pragma unroll
            for (int m = 0; m < 2; ++m) {
                int r = wr + m * 16 + fr;
                int byt = (kk * 64 + fk) ^ ((r & 7) << 4);
                af[m] = *(const bf16x8*)(&As[buf][r * 64 + (byt >> 1)]);
            }
            #pragma unroll
            for (int n = 0; n < 2; ++n) {
                int r = wc + n * 16 + fr;
                int byt = (kk * 64 + fk) ^ ((r & 7) << 4);
                bff[n] = *(const bf16x8*)(&Bs[buf][r * 64 + (byt >> 1)]);
            }
            #pragma unroll
            for (int m = 0; m < 2; ++m)
                #pragma unroll
                for (int n = 0; n < 2; ++n)
                    acc[m][n] = __builtin_amdgcn_mfma_f32_16x16x32_bf16(af[m], bff[n], acc[m][n], 0, 0, 0);
        }
    };

    load_tile(0);
    write_tile(0);
    __syncthreads();
    for (int t = 0; t < NT; ++t) {
        if (t + 1 < NT) load_tile(t + 1);
        compute(t & 1);
        if (t + 1 < NT) write_tile((t + 1) & 1);
        __syncthreads();
    }

    const int r0 = bm + wr + (lane >> 4) * 4;
    if (bn >= 3328) {
        // scalar strip: fp32 transposed for scan's coalesced reads
        #pragma unroll
        for (int n = 0; n < 2; ++n) {
            int col = bn + wc + n * 16 + fr;
            #pragma unroll
            for (int m = 0; m < 2; ++m)
                #pragma unroll
                for (int r = 0; r < 4; ++r)
                    DTA[(size_t)(col - 3328) * 512 + r0 + m * 16 + r] = acc[m][n][r];
        }
        return;
    }
    // stage full tile into LDS as bf16: Ts[local_row(t)][local_col(p)]
    #pragma unroll
    for (int m = 0; m < 2; ++m)
        #pragma unroll
        for (int n = 0; n < 2; ++n)
            #pragma unroll
            for (int r = 0; r < 4; ++r)
                Ts[wr + m * 16 + (lane >> 4) * 4 + r][wc + n * 16 + fr] =
                    f2bf(acc[m][n][r]);
    __syncthreads();
    if (bn < 3072) {
        // z or x -> transposed [(b*24+h)*64+p][t]
        const bool isX = bn >= 1536;
        const int hh = (bn - (isX ? 1536 : 0)) >> 6;
        const int bb = bm >> 8, l0 = bm & 255;
        ushort* dst = (isX ? XT : ZT);
        const int p = tid >> 2, t0 = (tid & 3) * 16;
        ushort* o = dst + ((size_t)(bb * NHEAD + hh) * HDIM + p) * SEQ + l0 + t0;
        #pragma unroll
        for (int k = 0; k < 16; ++k) o[k] = Ts[t0 + k][p];
    } else {
        // B/C -> compact row-major BC[row][256]
        const int c0 = bn - 3072;
        const int rr = tid >> 2, cs = (tid & 3) * 16;
        ushort* o = BC + (size_t)(bm + rr) * 256 + c0 + cs;
        #pragma unroll
        for (int k = 0; k < 16; ++k) o[k] = Ts[rr][cs + k];
    }
}

// ---------------- GEMM2 split-K: Part[s] = Yc(bf16) @ out_w^T -------------------
__global__ __launch_bounds__(256) void gemm2(const ushort* __restrict__ A,
        const float* __restrict__ W, float* __restrict__ Part) {
    const int bm = blockIdx.y * 64, bn = blockIdx.x * 64, ks = blockIdx.z;
    const int kbase = ks * 384;
    const int tid = threadIdx.x;
    const int wv = tid >> 6, lane = tid & 63;
    const int wr = (wv >> 1) * 32, wc = (wv & 1) * 32;
    __shared__ ushort As[2][64 * 64];
    __shared__ ushort Bs[2][64 * 64];
    const int srow = tid >> 4, sc4 = tid & 15;
    const int arow = tid >> 3, acol = (tid & 7) * 8;
    const int NT = 6;
    uint4 ra[2];
    float4 rw[4];

    auto load_tile = [&](int t) {
        const int k0 = kbase + t * 64;
        #pragma unroll
        for (int p = 0; p < 2; ++p)
            ra[p] = *(const uint4*)(A + (size_t)(bm + p * 32 + arow) * DIEXP + k0 + acol);
        #pragma unroll
        for (int p = 0; p < 4; ++p)
            rw[p] = *(const float4*)(W + (size_t)(bn + p * 16 + srow) * DIEXP + k0 + sc4 * 4);
    };
    auto write_tile = [&](int buf) {
        #pragma unroll
        for (int p = 0; p < 2; ++p) {
            int r = p * 32 + arow;
            int byt = (acol * 2) ^ ((r & 7) << 4);
            *(uint4*)(&As[buf][r * 64 + (byt >> 1)]) = ra[p];
        }
        #pragma unroll
        for (int p = 0; p < 4; ++p) {
            int r = p * 16 + srow;
            int byt = (sc4 * 8) ^ ((r & 7) << 4);
            ushort4 h;
            h.x = f2bf(rw[p].x); h.y = f2bf(rw[p].y);
            h.z = f2bf(rw[p].z); h.w = f2bf(rw[p].w);
            *(ushort4*)(&Bs[buf][r * 64 + (byt >> 1)]) = h;
        }
    };

    f32x4 acc[2][2];
    #pragma unroll
    for (int m = 0; m < 2; ++m)
        #pragma unroll
        for (int n = 0; n < 2; ++n) acc[m][n] = (f32x4){0.f, 0.f, 0.f, 0.f};
    const int fr = lane & 15, fk = (lane >> 4) * 16;

    auto compute = [&](int buf) {
        #pragma unroll
        for (int kk = 0; kk < 2; ++kk) {
            bf16x8 af[2], bff[2];
            #pragma unroll
            for (int m = 0; m < 2; ++m) {
                int r = wr + m * 16 + fr;
                int byt = (kk * 64 + fk) ^ ((r & 7) << 4);
                af[m] = *(const bf16x8*)(&As[buf][r * 64 + (byt >> 1)]);
            }
            #pragma unroll
            for (int n = 0; n < 2; ++n) {
                int r = wc + n * 16 + fr;
                int byt = (kk * 64 + fk) ^ ((r & 7) << 4);
                bff[n] = *(const bf16x8*)(&Bs[buf][r * 64 + (byt >> 1)]);
            }
            #pragma unroll
            for (int m = 0; m < 2; ++m)
                #pragma unroll
                for (int n = 0; n < 2; ++n)
                    acc[m][n] = __builtin_amdgcn_mfma_f32_16x16x32_bf16(af[m], bff[n], acc[m][n], 0, 0, 0);
        }
    };

    load_tile(0);
    write_tile(0);
    __syncthreads();
    for (int t = 0; t < NT; ++t) {
        if (t + 1 < NT) load_tile(t + 1);
        compute(t & 1);
        if (t + 1 < NT) write_tile((t + 1) & 1);
        __syncthreads();
    }

    const int r0 = bm + wr + (lane >> 4) * 4;
    float* P = Part + (size_t)ks * 512 * DMODL;
    #pragma unroll
    for (int n = 0; n < 2; ++n) {
        int col = bn + wc + n * 16 + fr;
        #pragma unroll
        for (int m = 0; m < 2; ++m)
            #pragma unroll
            for (int r = 0; r < 4; ++r)
                P[(size_t)(r0 + m * 16 + r) * DMODL + col] = acc[m][n][r];
    }
}

// ---------------- reduce4: out = sum_s Part[s] ----------------------------------
__global__ void reduce4(const float* __restrict__ Part, float* __restrict__ out) {
    const int i = blockIdx.x * 256 + threadIdx.x;   // float4 index, 98304 total
    const float4* p4 = (const float4*)Part;
    float4 a = p4[i];
    float4 b = p4[i + 98304];
    float4 c = p4[i + 196608];
    float4 d = p4[i + 294912];
    float4 r;
    r.x = a.x + b.x + c.x + d.x;
    r.y = a.y + b.y + c.y + d.y;
    r.z = a.z + b.z + c.z + d.z;
    r.w = a.w + b.w + c.w + d.w;
    ((float4*)out)[i] = r;
}

// ---------------- scan: scalars + wave-parallel cumsums (reads DTA only) -------
__global__ __launch_bounds__(256) void scan_kernel(const float* __restrict__ DTA,
        const float* __restrict__ dt_bias, float* __restrict__ DTv,
        float* __restrict__ lamv, float* __restrict__ Pc, float* __restrict__ theta) {
    const int bh = blockIdx.x;
    const int b = bh / NHEAD, h = bh % NHEAD;
    const int tid = threadIdx.x;
    __shared__ float mm[SEQ][18];
    const int l = tid;
    const int gl = b * SEQ + l;
    float DT  = softplusf(DTA[(size_t)h * 512 + gl] + dt_bias[h]);
    float Asp = fmaxf(softplusf(DTA[(size_t)(24 + h) * 512 + gl]), AFLOOR);
    float la  = -Asp * DT;
    float lam = sigmoidf_(DTA[(size_t)(48 + h) * 512 + gl]);
    DTv[bh * SEQ + l] = DT;
    lamv[bh * SEQ + l] = lam;
    #pragma unroll
    for (int i = 0; i < NANG; ++i) mm[l][i] = DT * DTA[(size_t)(72 + i) * 512 + gl];
    mm[l][16] = la;
    __syncthreads();
    const int wv = tid >> 6, lane = tid & 63;
    for (int ch = wv; ch < 17; ch += 4) {
        float carry = 0.f;
        for (int seg = 0; seg < 4; ++seg) {
            float v = mm[seg * 64 + lane][ch];
            #pragma unroll
            for (int off = 1; off < 64; off <<= 1) {
                float t = __shfl_up(v, off);
                if (lane >= off) v += t;
            }
            v += carry;
            carry = __shfl(v, 63);
            int ll = seg * 64 + lane;
            if (ch < 16)
                theta[((size_t)(b * SEQ + ll) * NHEAD + h) * NANG + ch] = v;
            else
                Pc[bh * SEQ + ll] = v;
        }
    }
}

// ---------------- prep3: RMS-norm + bias + RoPE -> bf16 Bh, Ch (from BC) --------
__global__ __launch_bounds__(256) void prep3(const ushort* __restrict__ BC,
        const float* __restrict__ Bbias, const float* __restrict__ Cbias,
        const float* __restrict__ Bnw, const float* __restrict__ Cnw,
        const float* __restrict__ theta,
        ushort* __restrict__ Bh, ushort* __restrict__ Ch) {
    int bl = blockIdx.x;
    int b = bl / SEQ, l = bl % SEQ;
    int tid = threadIdx.x;
    __shared__ float sB[RRANK][NSTATE], sC[RRANK][NSTATE], scale[4];
    __shared__ float thl[NHEAD * NANG];
    const ushort* row = BC + (size_t)bl * 256;
    if (tid < 128) {
        int r = tid / 64, n = tid % 64;
        sB[r][n] = bf2f(row[r * 64 + n]);
    } else {
        int t2 = tid - 128;
        int r = t2 / 64, n = t2 % 64;
        sC[r][n] = bf2f(row[128 + r * 64 + n]);
    }
    for (int k = tid; k < NHEAD * NANG; k += 256)
        thl[k] = theta[(size_t)bl * NHEAD * NANG + k];
    __syncthreads();
    int g = tid / 64, lane = tid % 64;
    float v = (g < 2) ? sB[g][lane] : sC[g - 2][lane];
    float ss = v * v;
    #pragma unroll
    for (int off = 32; off; off >>= 1) ss += __shfl_xor(ss, off);
    if (lane == 0) scale[g] = rsqrtf(ss / NSTATE + EPSV);
    __syncthreads();
    float scB[2] = {scale[0], scale[1]};
    float scC[2] = {scale[2], scale[3]};
    for (int idx = tid; idx < RRANK * NHEAD * NSTATE; idx += 256) {
        int n = idx % NSTATE;
        int h = (idx / NSTATE) % NHEAD;
        int r = idx / (NSTATE * NHEAD);
        float outB, outC;
        if (n < HALFSPLIT) {
            int i = n >> 1;
            int n0 = i * 2, n1 = n0 + 1;
            float th = thl[h * NANG + i];
            float c = cosf(th), s = sinf(th);
            float b0 = sB[r][n0] * scB[r] * Bnw[n0] * Bbias[(h * RRANK + r) * NSTATE + n0];
            float b1 = sB[r][n1] * scB[r] * Bnw[n1] * Bbias[(h * RRANK + r) * NSTATE + n1];
            float c0 = sC[r][n0] * scC[r] * Cnw[n0] * Cbias[(h * RRANK + r) * NSTATE + n0];
            float c1 = sC[r][n1] * scC[r] * Cnw[n1] * Cbias[(h * RRANK + r) * NSTATE + n1];
            outB = (n & 1) ? (b0 * s + b1 * c) : (b0 * c - b1 * s);
            outC = (n & 1) ? (c0 * s + c1 * c) : (c0 * c - c1 * s);
        } else {
            outB = sB[r][n] * scB[r] * Bnw[n] * Bbias[(h * RRANK + r) * NSTATE + n];
            outC = sC[r][n] * scC[r] * Cnw[n] * Cbias[(h * RRANK + r) * NSTATE + n];
        }
        size_t o = ((size_t)((b * RRANK + r) * NHEAD + h) * SEQ + l) * NSTATE + n;
        Bh[o] = f2bf(outB);
        Ch[o] = f2bf(outC);
    }
}

// ---------------- att2: MFMA scan + fused combine/gate --------------------------
// block = (bh, tt). Per jt: both r2 Grams (MFMA back-to-back), SHARED decay
// weight table w[nf][r] once with __expf, Pld writes, 16 back-to-back PV MFMAs.
// Combine reads x/z from XT/ZT (bf16, coalesced).
__global__ __launch_bounds__(256) void att2(const ushort* __restrict__ Bh,
        const ushort* __restrict__ Ch, const ushort* __restrict__ XT,
        const ushort* __restrict__ ZT, const float* __restrict__ Pc,
        const float* __restrict__ DTv, const float* __restrict__ lamv,
        const float* __restrict__ mimo_x, const float* __restrict__ mimo_o,
        const float* __restrict__ Dvec, ushort* __restrict__ Yc) {
    const int bh = blockIdx.x, tt = blockIdx.y;
    const int b = bh / NHEAD, h = bh % NHEAD;
    const int tid = threadIdx.x, wv = tid >> 6, lane = tid & 63;
    __shared__ float Pl[SEQ], u1s[SEQ], u2s[SEQ];
    __shared__ ushort Pld[2][4][16][72];
    for (int t = tid; t < SEQ; t += 256) {
        Pl[t]  = Pc[bh * SEQ + t];
        u1s[t] = DTv[bh * SEQ + t] * lamv[bh * SEQ + t];
        u2s[t] = (t + 1 < SEQ) ? DTv[bh * SEQ + t + 1] * (1.f - lamv[bh * SEQ + t + 1]) : 0.f;
    }
    __syncthreads();
    const int r16 = lane & 15, kg = (lane >> 4) * 8;
    const int trow = tt * 64 + wv * 16;
    const int tr0 = trow + (lane >> 4) * 4;
    const int brh0 = (b * RRANK + 0) * NHEAD + h;
    const int brh1 = (b * RRANK + 1) * NHEAD + h;
    bf16x8 ca[2][2];
    {
        const ushort* cp0 = Ch + ((size_t)brh0 * SEQ + trow + r16) * NSTATE + kg;
        const ushort* cp1 = Ch + ((size_t)brh1 * SEQ + trow + r16) * NSTATE + kg;
        ca[0][0] = *(const bf16x8*)cp0;  ca[0][1] = *(const bf16x8*)(cp0 + 32);
        ca[1][0] = *(const bf16x8*)cp1;  ca[1][1] = *(const bf16x8*)(cp1 + 32);
    }
    f32x4 yacc[2][4];
    #pragma unroll
    for (int r2 = 0; r2 < 2; ++r2)
        #pragma unroll
        for (int pf = 0; pf < 4; ++pf) yacc[r2][pf] = (f32x4){0.f, 0.f, 0.f, 0.f};
    float Pt[4];
    #pragma unroll
    for (int r = 0; r < 4; ++r) Pt[r] = Pl[tr0 + r];
    const float Dh = Dvec[h];

    for (int jt = 0; jt <= tt; ++jt) {
        // PV operand tiles (L2-resident)
        bf16x8 xf[4][2];
        #pragma unroll
        for (int pf = 0; pf < 4; ++pf) {
            const ushort* xp = XT + ((size_t)bh * HDIM + pf * 16 + r16) * SEQ + jt * 64 + kg;
            xf[pf][0] = *(const bf16x8*)xp;
            xf[pf][1] = *(const bf16x8*)(xp + 32);
        }
        // Grams for both r2 (independent MFMA chains, issued back-to-back)
        f32x4 g[2][4];
        #pragma unroll
        for (int r2 = 0; r2 < 2; ++r2) {
            const size_t bbase = (size_t)(r2 ? brh1 : brh0) * SEQ;
            #pragma unroll
            for (int nf = 0; nf < 4; ++nf) {
                const ushort* bp = Bh + (bbase + jt * 64 + nf * 16 + r16) * NSTATE + kg;
                bf16x8 b0 = *(const bf16x8*)bp;
                bf16x8 b1 = *(const bf16x8*)(bp + 32);
                f32x4 gg = (f32x4){0.f, 0.f, 0.f, 0.f};
                gg = __builtin_amdgcn_mfma_f32_16x16x32_bf16(ca[r2][0], b0, gg, 0, 0, 0);
                gg = __builtin_amdgcn_mfma_f32_16x16x32_bf16(ca[r2][1], b1, gg, 0, 0, 0);
                g[r2][nf] = gg;
            }
        }
        // SHARED decay weights (r2-independent; VALU fills the MFMA shadow)
        float w[4][4];
        #pragma unroll
        for (int nf = 0; nf < 4; ++nf) {
            const int j = jt * 64 + nf * 16 + r16;
            const float Pj = Pl[j], v1 = u1s[j], v2 = u2s[j];
            #pragma unroll
            for (int r = 0; r < 4; ++r) {
                const int t = tr0 + r;
                w[nf][r] = (j <= t) ? __expf(Pt[r] - Pj) * (v1 + ((j < t) ? v2 : 0.f)) : 0.f;
            }
        }
        // combine -> Pld (bf16 A-fragment layout)
        #pragma unroll
        for (int r2 = 0; r2 < 2; ++r2)
            #pragma unroll
            for (int nf = 0; nf < 4; ++nf)
                #pragma unroll
                for (int r = 0; r < 4; ++r)
                    Pld[r2][wv][(lane >> 4) * 4 + r][nf * 16 + r16] = f2bf(g[r2][nf][r] * w[nf][r]);
        // PV (16 back-to-back MFMAs)
        #pragma unroll
        for (int r2 = 0; r2 < 2; ++r2) {
            bf16x8 pa0 = *(const bf16x8*)&Pld[r2][wv][r16][kg];
            bf16x8 pa1 = *(const bf16x8*)&Pld[r2][wv][r16][32 + kg];
            #pragma unroll
            for (int pf = 0; pf < 4; ++pf) {
                yacc[r2][pf] = __builtin_amdgcn_mfma_f32_16x16x32_bf16(pa0, xf[pf][0], yacc[r2][pf], 0, 0, 0);
                yacc[r2][pf] = __builtin_amdgcn_mfma_f32_16x16x32_bf16(pa1, xf[pf][1], yacc[r2][pf], 0, 0, 0);
            }
        }
    }
    // fused combine: y = y0*mm0 + y1*mm1 + D*x, gated by silu(z), -> bf16 Yc
    #pragma unroll
    for (int pf = 0; pf < 4; ++pf) {
        const int p = pf * 16 + r16;
        const float mm0 = mimo_x[(h * RRANK + 0) * HDIM + p] * mimo_o[(h * RRANK + 0) * HDIM + p];
        const float mm1 = mimo_x[(h * RRANK + 1) * HDIM + p] * mimo_o[(h * RRANK + 1) * HDIM + p];
        ushort4 xv4 = *(const ushort4*)&XT[((size_t)bh * HDIM + p) * SEQ + tr0];
        ushort4 zv4 = *(const ushort4*)&ZT[((size_t)bh * HDIM + p) * SEQ + tr0];
        const ushort* xvp = (const ushort*)&xv4;
        const ushort* zvp = (const ushort*)&zv4;
        #pragma unroll
        for (int r = 0; r < 4; ++r) {
            const int t = tr0 + r;
            float xv = bf2f(xvp[r]);
            float zv = bf2f(zvp[r]);
            float y = yacc[0][pf][r] * mm0 + yacc[1][pf][r] * mm1 + Dh * xv;
            y *= zv * sigmoidf_(zv);
            Yc[(size_t)(b * SEQ + t) * DIEXP + h * HDIM + p] = f2bf(y);
        }
    }
}

// ---------------- launch ----------------
extern "C" void kernel_launch(void* const* d_in, const int* in_sizes, int n_in,
                              void* d_out, int out_size, void* d_ws, size_t ws_size,
                              hipStream_t stream) {
    const float* u        = (const float*)d_in[0];
    const float* in_w     = (const float*)d_in[1];
    const float* dt_bias  = (const float*)d_in[2];
    const float* B_bias   = (const float*)d_in[3];
    const float* C_bias   = (const float*)d_in[4];
    const float* B_norm_w = (const float*)d_in[5];
    const float* C_norm_w = (const float*)d_in[6];
    const float* mimo_x   = (const float*)d_in[7];
    const float* mimo_o   = (const float*)d_in[8];
    const float* Dvec     = (const float*)d_in[9];
    const float* out_w    = (const float*)d_in[10];
    float* out = (float*)d_out;

    // workspace layout (float offsets), full sizes audited:
    //   ZT   [0,        393216)  : 2*24*64*256 bf16 = 786,432 us = 393,216 f
    //   XT   [393216,   786432)  : 786,432 us
    //   BC   [786432,   851968)  : 512*256 bf16 = 131,072 us = 65,536 f
    //   DTA  [851968,   917504)  : 128*512 f = 65,536 f
    //   Bh   [917504,  1703936)  : 96*256*64 bf16 = 1,572,864 us = 786,432 f
    //   Ch   [1703936, 2490368)  : 786,432 f
    //   theta[2490368, 2686976)  : 196,608 f
    //   Pc   [2686976, 2699264)  : 12,288 f
    //   DTv  [2699264, 2711552)  : 12,288 f
    //   lamv [2711552, 2723840)  : 12,288 f
    //   Yc   [2723840, 3117056)  : 512*1536 bf16 = 786,432 us = 393,216 f
    //   Part [3117056, 4689920)  : 4*512*768 f = 1,572,864 f   (~18.8 MB total)
    float* ws = (float*)d_ws;
    ushort* ZT    = (ushort*)(ws);
    ushort* XT    = (ushort*)(ws + 393216);
    ushort* BC    = (ushort*)(ws + 786432);
    float*  DTA   = ws + 851968;
    ushort* Bh_bf = (ushort*)(ws + 917504);
    ushort* Ch_bf = (ushort*)(ws + 1703936);
    float*  theta = ws + 2490368;
    float*  Pc    = ws + 2686976;
    float*  DTv   = ws + 2699264;
    float*  lamv  = ws + 2711552;
    ushort* Yc_bf = (ushort*)(ws + 2723840);
    float*  Part  = ws + 3117056;

    // 1) routed projection: ZT/XT (transposed bf16), BC (bf16), DTA (fp32 strip)
    gemm1<<<dim3(DINP_PAD / 64, 8), 256, 0, stream>>>(u, in_w, ZT, XT, BC, DTA);
    // 2) scalars + wave-parallel cumsums (P, theta)
    scan_kernel<<<BATCH * NHEAD, 256, 0, stream>>>(DTA, dt_bias, DTv, lamv, Pc, theta);
    // 3) RMS + bias + RoPE -> bf16 Bh/Ch
    prep3<<<BATCH * SEQ, 256, 0, stream>>>(BC, B_bias, C_bias, B_norm_w, C_norm_w,
                                           theta, Bh_bf, Ch_bf);
    // 4) MFMA scan + fused combine -> bf16 Yc
    att2<<<dim3(BATCH * NHEAD, 4), 256, 0, stream>>>(Bh_bf, Ch_bf, XT, ZT, Pc, DTv,
                                                     lamv, mimo_x, mimo_o, Dvec, Yc_bf);
    // 5) split-K GEMM2 partials; 384 blocks
    gemm2<<<dim3(DMODL / 64, 8, 4), 256, 0, stream>>>(Yc_bf, out_w, Part);
    // 6) out = sum of 4 partials
    reduce4<<<384, 256, 0, stream>>>(Part, out);
}